// Round 9
// baseline (2541.575 us; speedup 1.0000x reference)
//
#include <hip/hip_runtime.h>
#include <hip/hip_bf16.h>
#include <hip/hip_fp8.h>
#include <math.h>

// TFT: B=32, T=512, V=16, D=256, H=4, L=2.  BT = 16384.
// Round 9: distributed-overhead harvest:
//  - xi in bf16 (wih GEMM emits bf16; LSTM loads halved)
//  - LSTM acc init via zero-operand MFMA (no per-step 32x v_mov)
//  - add2 fused into mgemm (ADT=3: A=A1+A2) and grn_epi (two skips)
//  - one-pass LN (sum+sumsq in one float2 shuffle reduction)
// LSTM core: 32 blocks x 512 thr, K=128 scaled fp8 MFMA, weights in regs (R8).

#define BT 16384
#define TT 512
#define BB 32
#define VV 16
#define DD 256

typedef unsigned short ushort;
typedef unsigned int uint;
typedef unsigned long ulong_;
typedef __attribute__((ext_vector_type(8))) short short8;
typedef __attribute__((ext_vector_type(8))) unsigned short ushort8v;
typedef __attribute__((ext_vector_type(4))) float floatx4;
typedef __attribute__((ext_vector_type(8))) int int8v;

#if __has_builtin(__builtin_amdgcn_cvt_pk_fp8_f32)
#define HW_FP8_CVT 1
#endif

__device__ __forceinline__ float sigmoidf_(float x) { return 1.f / (1.f + expf(-x)); }
__device__ __forceinline__ float eluf_(float x)     { return x > 0.f ? x : expm1f(x); }
__device__ __forceinline__ float fsig(float x) {
  return __builtin_amdgcn_rcpf(1.f + __expf(-x));
}
__device__ __forceinline__ float ftanh(float x) {
  float xc = fminf(fmaxf(x, -44.f), 44.f);
  float e = __expf(-2.f * xc);
  return (1.f - e) * __builtin_amdgcn_rcpf(1.f + e);
}
__device__ __forceinline__ ushort f2bf(float f) {
  unsigned int u = __float_as_uint(f);
  unsigned int r = u + 0x7fffu + ((u >> 16) & 1u);
  return (ushort)(r >> 16);
}
__device__ __forceinline__ float bf2f(ushort b) { return __uint_as_float(((unsigned int)b) << 16); }

// dual block-wide sum over 256 threads (one shuffle pass, one barrier pair)
__device__ __forceinline__ float2 bsum256x2(float a, float b, float* red8) {
  #pragma unroll
  for (int m = 32; m > 0; m >>= 1) { a += __shfl_xor(a, m, 64); b += __shfl_xor(b, m, 64); }
  int w = threadIdx.x >> 6;
  if ((threadIdx.x & 63) == 0) { red8[w * 2] = a; red8[w * 2 + 1] = b; }
  __syncthreads();
  float ra = red8[0] + red8[2] + red8[4] + red8[6];
  float rb = red8[1] + red8[3] + red8[5] + red8[7];
  __syncthreads();
  return make_float2(ra, rb);
}

__device__ __forceinline__ float block_sum256(float v, float* red) {
  int j = threadIdx.x;
  red[j] = v; __syncthreads();
  #pragma unroll
  for (int st = 128; st > 0; st >>= 1) {
    if (j < st) red[j] += red[j + st];
    __syncthreads();
  }
  float r = red[0];
  __syncthreads();
  return r;
}

// ---------------- weight prep ----------------
__global__ void wtT_k(const float* __restrict__ src, ushort* __restrict__ dst,
                      int K, int N, long sStride, long dStride) {
  int b = blockIdx.z;
  src += (size_t)b * sStride; dst += (size_t)b * dStride;
  __shared__ float t[32][33];
  int k0 = blockIdx.y * 32, n0 = blockIdx.x * 32;
  int tx = threadIdx.x & 31, ty = threadIdx.x >> 5;
  #pragma unroll
  for (int i = 0; i < 32; i += 8) {
    int k = k0 + ty + i, n = n0 + tx;
    t[ty + i][tx] = (k < K && n < N) ? src[(size_t)k * N + n] : 0.f;
  }
  __syncthreads();
  #pragma unroll
  for (int i = 0; i < 32; i += 8) {
    int n = n0 + ty + i, k = k0 + tx;
    if (n < N && k < K) dst[(size_t)n * K + k] = f2bf(t[tx][ty + i]);
  }
}

__global__ void cvt_k(const float* __restrict__ src, ushort* __restrict__ dst, int n) {
  int i = blockIdx.x * 256 + threadIdx.x;
  if (i < n) dst[i] = f2bf(src[i]);
}

// pack whh fp32 [2][1024][256] -> fp8 e4m3 (x64) in K=128 B-frag order.
__global__ void whh_pack8_k(const float* __restrict__ whh, unsigned char* __restrict__ dst) {
  int gid = blockIdx.x * 256 + threadIdx.x;   // 16384 total
  int layer = gid >> 13;
  int rem = gid & 8191;
  int lane = rem & 63;
  int f = (rem >> 6) & 15;
  int wave = rem >> 10;
  int kt2 = f & 1, ts = (f >> 1) & 1, g = f >> 2;
  int n = g * 256 + wave * 32 + ts * 16 + (lane & 15);
  int k0 = kt2 * 128 + (lane >> 4) * 32;
  const float* src = whh + (size_t)layer * 262144 + (size_t)n * 256 + k0;
  unsigned char* d = dst + (size_t)gid * 32;
  #pragma unroll
  for (int b = 0; b < 32; b++) {
    __hip_fp8_e4m3 q(src[b] * 64.f);
    d[b] = q.__x;
  }
}

// ---------------- bf16 MFMA GEMM ----------------
// ADT: 0 A fp32; 1 A bf16; 2 embedded-on-the-fly; 3 A = A1+A2 fp32 (A2 via embw)
template<int ADT, int ACT, int CDT>
__global__ __launch_bounds__(256) void mgemm_k(
    const void* __restrict__ Aall, int lda, long aStride,
    const ushort* __restrict__ Ball, long bStride,
    const float* __restrict__ biasAll, long biasStride,
    void* __restrict__ Call, int ldc, long cStride,
    int K, int Nvalid,
    const float* __restrict__ embw, const float* __restrict__ embb, int xbase) {
  int z = blockIdx.z;
  const ushort* B = Ball + (size_t)z * bStride;
  const float* bias = biasAll ? biasAll + (size_t)z * biasStride : nullptr;
  int m0 = blockIdx.y * 128, n0 = blockIdx.x * 128;
  __shared__ ushort As[128][40];
  __shared__ ushort Bs[128][40];
  int tid = threadIdx.x;
  int r = tid >> 1, half = tid & 1;
  int wave = tid >> 6, lane = tid & 63;
  int wm = (wave >> 1) * 64, wn = (wave & 1) * 64;
  int lm = lane & 15, lq = lane >> 4;
  floatx4 acc[4][4];
  #pragma unroll
  for (int i = 0; i < 4; i++)
    #pragma unroll
    for (int j = 0; j < 4; j++) acc[i][j] = (floatx4)0.f;

  for (int k0 = 0; k0 < K; k0 += 32) {
    int kk = k0 + half * 16;
    {
      int gm = m0 + r;
      ushort tmp[16];
      if (ADT == 0) {
        const float* Af = (const float*)Aall + (size_t)z * aStride + (size_t)gm * lda + kk;
        #pragma unroll
        for (int q = 0; q < 4; q++) {
          float4 f = ((const float4*)Af)[q];
          tmp[q * 4 + 0] = f2bf(f.x); tmp[q * 4 + 1] = f2bf(f.y);
          tmp[q * 4 + 2] = f2bf(f.z); tmp[q * 4 + 3] = f2bf(f.w);
        }
      } else if (ADT == 1) {
        const ushort* Ab = (const ushort*)Aall + (size_t)z * aStride + (size_t)gm * lda + kk;
        *(ushort8v*)&tmp[0] = *(const ushort8v*)(Ab);
        *(ushort8v*)&tmp[8] = *(const ushort8v*)(Ab + 8);
      } else if (ADT == 2) {
        const float* xp = (const float*)Aall;
        float xv = xp[(size_t)gm * lda + xbase + z + (kk >> 8)];
        const float4* ew = (const float4*)(embw + (size_t)z * 256 + kk);
        const float4* eb = (const float4*)(embb + (size_t)z * 256 + kk);
        #pragma unroll
        for (int q = 0; q < 4; q++) {
          float4 w4 = ew[q], b4 = eb[q];
          tmp[q * 4 + 0] = f2bf(xv * w4.x + b4.x); tmp[q * 4 + 1] = f2bf(xv * w4.y + b4.y);
          tmp[q * 4 + 2] = f2bf(xv * w4.z + b4.z); tmp[q * 4 + 3] = f2bf(xv * w4.w + b4.w);
        }
      } else {
        const float* A1 = (const float*)Aall + (size_t)z * aStride + (size_t)gm * lda + kk;
        const float* A2 = embw + (size_t)z * aStride + (size_t)gm * lda + kk;
        #pragma unroll
        for (int q = 0; q < 4; q++) {
          float4 f1 = ((const float4*)A1)[q];
          float4 f2 = ((const float4*)A2)[q];
          tmp[q * 4 + 0] = f2bf(f1.x + f2.x); tmp[q * 4 + 1] = f2bf(f1.y + f2.y);
          tmp[q * 4 + 2] = f2bf(f1.z + f2.z); tmp[q * 4 + 3] = f2bf(f1.w + f2.w);
        }
      }
      *(ushort8v*)&As[r][half * 16]     = *(ushort8v*)&tmp[0];
      *(ushort8v*)&As[r][half * 16 + 8] = *(ushort8v*)&tmp[8];
    }
    {
      int gn = n0 + r;
      ushort tmp[16];
      if (gn < Nvalid) {
        const ushort* Bp = B + (size_t)gn * K + kk;
        *(ushort8v*)&tmp[0] = *(const ushort8v*)(Bp);
        *(ushort8v*)&tmp[8] = *(const ushort8v*)(Bp + 8);
      } else {
        #pragma unroll
        for (int q = 0; q < 16; q++) tmp[q] = 0;
      }
      *(ushort8v*)&Bs[r][half * 16]     = *(ushort8v*)&tmp[0];
      *(ushort8v*)&Bs[r][half * 16 + 8] = *(ushort8v*)&tmp[8];
    }
    __syncthreads();
    short8 fa[4], fb[4];
    #pragma unroll
    for (int i = 0; i < 4; i++) fa[i] = *(const short8*)&As[wm + i * 16 + lm][lq * 8];
    #pragma unroll
    for (int j = 0; j < 4; j++) fb[j] = *(const short8*)&Bs[wn + j * 16 + lm][lq * 8];
    #pragma unroll
    for (int i = 0; i < 4; i++)
      #pragma unroll
      for (int j = 0; j < 4; j++)
        acc[i][j] = __builtin_amdgcn_mfma_f32_16x16x32_bf16(fa[i], fb[j], acc[i][j], 0, 0, 0);
    __syncthreads();
  }
  #pragma unroll
  for (int j = 0; j < 4; j++) {
    int gn = n0 + wn + j * 16 + lm;
    if (gn >= Nvalid) continue;
    float bv = bias ? bias[gn] : 0.f;
    #pragma unroll
    for (int i = 0; i < 4; i++) {
      #pragma unroll
      for (int rg = 0; rg < 4; rg++) {
        int gm = m0 + wm + i * 16 + lq * 4 + rg;
        float v = acc[i][j][rg] + bv;
        if (ACT == 1) v = eluf_(v);
        if (CDT == 0) ((float*)Call + (size_t)z * cStride)[(size_t)gm * ldc + gn] = v;
        else ((ushort*)Call + (size_t)z * cStride)[(size_t)gm * ldc + gn] = f2bf(v);
      }
    }
  }
}

// ---------------- selection GRN finish ----------------
__global__ void sel_finish_k(const float* __restrict__ selG, const float* __restrict__ selSkip,
                             const float* __restrict__ lng, const float* __restrict__ lnb,
                             float* __restrict__ wout, int M) {
  int m = blockIdx.x * 256 + threadIdx.x;
  if (m >= M) return;
  float s[16];
  float mean = 0.f;
  #pragma unroll
  for (int i = 0; i < 16; i++) {
    float h1 = selG[m * 32 + i], h2 = selG[m * 32 + 16 + i];
    float val = h1 * sigmoidf_(h2) + selSkip[m * 16 + i];
    s[i] = val; mean += val;
  }
  mean *= (1.f / 16.f);
  float var = 0.f;
  #pragma unroll
  for (int i = 0; i < 16; i++) { float d = s[i] - mean; var += d * d; }
  var *= (1.f / 16.f);
  float inv = rsqrtf(var + 1e-5f);
  float mx = -1e30f;
  #pragma unroll
  for (int i = 0; i < 16; i++) { s[i] = (s[i] - mean) * inv * lng[i] + lnb[i]; mx = fmaxf(mx, s[i]); }
  float sum = 0.f;
  #pragma unroll
  for (int i = 0; i < 16; i++) { s[i] = expf(s[i] - mx); sum += s[i]; }
  float isum = 1.f / sum;
  #pragma unroll
  for (int i = 0; i < 16; i++) wout[m * 16 + i] = s[i] * isum;
}

// ---------------- var-GRN epilogue, 4 variables per launch, one-pass LN ----------------
__global__ __launch_bounds__(256) void var_epi4_k(
    const ushort* __restrict__ G16,
    const float* __restrict__ x, int vbase,
    const float* __restrict__ embw, const float* __restrict__ embb,
    const float* __restrict__ lng, const float* __restrict__ lnb,
    const float* __restrict__ wts, float* __restrict__ vsn, int first) {
  int m = blockIdx.x, j = threadIdx.x;
  __shared__ float red8[8];
  float accv = 0.f;
  #pragma unroll
  for (int z = 0; z < 4; z++) {
    int v = vbase + z;
    const ushort* Gp = G16 + ((size_t)z * BT + m) * 512;
    float g1 = bf2f(Gp[j]), g2 = bf2f(Gp[256 + j]);
    float e = x[m * VV + v] * embw[z * 256 + j] + embb[z * 256 + j];
    float s = g1 * sigmoidf_(g2) + e;
    float2 r = bsum256x2(s, s * s, red8);
    float mean = r.x * (1.f / 256.f);
    float var = r.y * (1.f / 256.f) - mean * mean;
    float o = (s - mean) * rsqrtf(var + 1e-5f) * lng[z * 256 + j] + lnb[z * 256 + j];
    accv += wts[m * VV + v] * o;
  }
  size_t oi = (size_t)m * 256 + j;
  if (first) vsn[oi] = accv; else vsn[oi] += accv;
}

// ---------------- generic GRN epilogue: GLU + (skipA+skipB) + LN, one-pass ----------------
__global__ __launch_bounds__(256) void grn_epi_k(
    const ushort* __restrict__ G, const float* __restrict__ skipA,
    const float* __restrict__ skipB,
    const float* __restrict__ lng, const float* __restrict__ lnb,
    float* __restrict__ out) {
  int m = blockIdx.x, j = threadIdx.x;
  __shared__ float red8[8];
  float g1 = bf2f(G[(size_t)m * 512 + j]), g2 = bf2f(G[(size_t)m * 512 + 256 + j]);
  float sk = skipA[(size_t)m * 256 + j];
  if (skipB) sk += skipB[(size_t)m * 256 + j];
  float s = g1 * sigmoidf_(g2) + sk;
  float2 r = bsum256x2(s, s * s, red8);
  float mean = r.x * (1.f / 256.f);
  float var = r.y * (1.f / 256.f) - mean * mean;
  out[(size_t)m * 256 + j] = (s - mean) * rsqrtf(var + 1e-5f) * lng[j] + lnb[j];
}

// ---------------- elementwise ----------------
__global__ void add2_k(const float* __restrict__ a, const float* __restrict__ b,
                       float* __restrict__ c, int n) {
  int i = blockIdx.x * 256 + threadIdx.x;
  if (i < n) c[i] = a[i] + b[i];
}

// ---------------- LSTM recurrence: K=128 scaled fp8 MFMA (R8 core, bf16 xi) ----------------
#define DESC (1.f / 1024.f)
#define H8S 272
__global__ __launch_bounds__(512, 2) void lstm_recur_k(
    const ushort* __restrict__ xi16,         // [B,T,1024] bf16 = xW^T + bih + bhh
    const unsigned char* __restrict__ wpk,   // fp8 K128-frag-packed layer (262144 B)
    float* __restrict__ hout,                // [B,T,256]
    int T) {
  int bb = blockIdx.x;                        // one batch
  int tid = threadIdx.x;
  int wave = tid >> 6, lane = tid & 63;
  int lm = lane & 15, lq = lane >> 4;
  __shared__ __align__(16) unsigned char h8[2][16 * H8S];
  for (int i = tid; i < 2 * 16 * H8S / 4; i += 512) ((uint*)h8)[i] = 0;

  int8v wr[16];
  {
    const int8v* wp = (const int8v*)wpk;
    #pragma unroll
    for (int f = 0; f < 16; f++) wr[f] = wp[(wave * 16 + f) * 64 + lane];
  }
  bool act = (lq == 0);
  int jj = wave * 32 + lm;                   // ts adds +16
  const ushort* xg = xi16 + (size_t)bb * T * 1024;
  float xq[8], xn[8];
  if (act) {
    #pragma unroll
    for (int g = 0; g < 4; g++) {
      xq[2 * g]     = bf2f(xg[g * 256 + jj]);
      xq[2 * g + 1] = bf2f(xg[g * 256 + jj + 16]);
    }
  }
  float cst[2] = {0.f, 0.f};
  float hbf[2][8];
  int arow = lm * H8S + lq * 32;
  const floatx4 z4 = (floatx4)0.f;
  __syncthreads();

  for (int t = 0; t < T; t++) {
    int cur = t & 1, nxt = cur ^ 1;
    if (act && t + 1 < T) {
      const ushort* xp = xg + (size_t)(t + 1) * 1024;
      #pragma unroll
      for (int g = 0; g < 4; g++) {
        xn[2 * g]     = bf2f(xp[g * 256 + jj]);
        xn[2 * g + 1] = bf2f(xp[g * 256 + jj + 16]);
      }
    }
    int8v a[2];
    #pragma unroll
    for (int kt = 0; kt < 2; kt++)
      a[kt] = *(const int8v*)&h8[cur][arow + kt * 128];
    floatx4 acc[8];                 // f = g*2 + ts
    #pragma unroll
    for (int f = 0; f < 8; f++)
      acc[f] = __builtin_amdgcn_mfma_scale_f32_16x16x128_f8f6f4(
          a[0], wr[f * 2 + 0], z4, 0, 0, 0, 0x7f7f7f7f, 0, 0x7f7f7f7f);
    #pragma unroll
    for (int f = 0; f < 8; f++)
      acc[f] = __builtin_amdgcn_mfma_scale_f32_16x16x128_f8f6f4(
          a[1], wr[f * 2 + 1], acc[f], 0, 0, 0, 0x7f7f7f7f, 0, 0x7f7f7f7f);
    if (act) {
      int tb = t & 7;
      #pragma unroll
      for (int ts = 0; ts < 2; ts++) {
        float pi = acc[0 + ts][0] * DESC + xq[0 + ts];
        float pf = acc[2 + ts][0] * DESC + xq[2 + ts];
        float pg = acc[4 + ts][0] * DESC + xq[4 + ts];
        float po = acc[6 + ts][0] * DESC + xq[6 + ts];
        float c = fsig(pf) * cst[ts] + fsig(pi) * ftanh(pg);
        cst[ts] = c;
        hbf[ts][tb] = fsig(po) * ftanh(c);
      }
#ifdef HW_FP8_CVT
      int pk = __builtin_amdgcn_cvt_pk_fp8_f32(hbf[0][tb] * 16.f, hbf[1][tb] * 16.f, 0, false);
      h8[nxt][jj]      = (unsigned char)(pk & 0xff);
      h8[nxt][jj + 16] = (unsigned char)((pk >> 8) & 0xff);
#else
      __hip_fp8_e4m3 q0(hbf[0][tb] * 16.f), q1(hbf[1][tb] * 16.f);
      h8[nxt][jj]      = q0.__x;
      h8[nxt][jj + 16] = q1.__x;
#endif
      if (tb == 7) {
        #pragma unroll
        for (int q = 0; q < 8; q++) {
          size_t base = ((size_t)(bb * T + t - 7 + q)) * 256;
          hout[base + jj]      = hbf[0][q];
          hout[base + jj + 16] = hbf[1][q];
        }
      }
      #pragma unroll
      for (int g = 0; g < 8; g++) xq[g] = xn[g];
    }
    __syncthreads();
  }
}

// ---------------- attention, decode-style (only query t = T-1) ----------------
__global__ __launch_bounds__(256) void attn_decode_k(const float* __restrict__ qkv,
                                                     float* __restrict__ o, int T) {
  int bh = blockIdx.x; int b = bh >> 2, h = bh & 3;
  int tid = threadIdx.x;
  __shared__ float q[64];
  __shared__ float p[512];
  __shared__ float red[256];
  if (tid < 64) q[tid] = qkv[((size_t)(b * T + T - 1)) * 768 + h * 64 + tid];
  __syncthreads();
  for (int t = tid; t < 512; t += 256) {
    const float* kv = qkv + ((size_t)(b * T + t)) * 768 + 256 + h * 64;
    float s = 0.f;
    #pragma unroll 16
    for (int d = 0; d < 64; d++) s += q[d] * kv[d];
    p[t] = s * 0.125f;
  }
  __syncthreads();
  red[tid] = fmaxf(p[tid], p[tid + 256]); __syncthreads();
  for (int st = 128; st > 0; st >>= 1) { if (tid < st) red[tid] = fmaxf(red[tid], red[tid + st]); __syncthreads(); }
  float mx = red[0]; __syncthreads();
  float e0 = expf(p[tid] - mx), e1 = expf(p[tid + 256] - mx);
  red[tid] = e0 + e1; __syncthreads();
  for (int st = 128; st > 0; st >>= 1) { if (tid < st) red[tid] += red[tid + st]; __syncthreads(); }
  float inv = 1.f / red[0];
  __syncthreads();
  p[tid] = e0; p[tid + 256] = e1;
  __syncthreads();
  int d = tid & 63, grp = tid >> 6;
  float acc = 0.f;
  for (int t = grp * 128; t < grp * 128 + 128; t++)
    acc += p[t] * qkv[((size_t)(b * T + t)) * 768 + 512 + h * 64 + d];
  red[tid] = acc; __syncthreads();
  if (grp == 0)
    o[(b * 4 + h) * 64 + d] = (red[tid] + red[tid + 64] + red[tid + 128] + red[tid + 192]) * inv;
}

// ---------------- attn out-proj + residual + LN (only t=T-1) ----------------
__global__ __launch_bounds__(256) void attn_proj_ln_k(
    const float* __restrict__ attnO, const float* __restrict__ W, const float* __restrict__ bias,
    const float* __restrict__ lstmF, const float* __restrict__ lng, const float* __restrict__ lnb,
    float* __restrict__ out, int T) {
  int bb = blockIdx.x, j = threadIdx.x;
  __shared__ float a[256];
  __shared__ float red[256];
  a[j] = attnO[bb * 256 + j];
  __syncthreads();
  float acc = bias[j];
  const float* wr = W + (size_t)j * 256;
  #pragma unroll 8
  for (int k = 0; k < 256; k += 4) {
    float4 w4 = *(const float4*)(wr + k);
    acc += a[k] * w4.x + a[k + 1] * w4.y + a[k + 2] * w4.z + a[k + 3] * w4.w;
  }
  float s = acc + lstmF[((size_t)(bb * T + T - 1)) * 256 + j];
  float mean = block_sum256(s, red) * (1.f / 256.f);
  float d = s - mean;
  float var = block_sum256(d * d, red) * (1.f / 256.f);
  out[bb * 256 + j] = d * rsqrtf(var + 1e-5f) * lng[j] + lnb[j];
}

// ---------------- final two GRNs (pa then fg), only t=T-1 ----------------
__global__ __launch_bounds__(256) void final_grns_k(
    const float* __restrict__ ain,
    const float* __restrict__ paw1, const float* __restrict__ pab1,
    const float* __restrict__ paw2, const float* __restrict__ pab2,
    const float* __restrict__ palg, const float* __restrict__ palb,
    const float* __restrict__ fgw1, const float* __restrict__ fgb1,
    const float* __restrict__ fgw2, const float* __restrict__ fgb2,
    const float* __restrict__ fglg, const float* __restrict__ fglb,
    float* __restrict__ out) {
  int bb = blockIdx.x, j = threadIdx.x;
  __shared__ float a[256];
  __shared__ float hbuf[1024];
  __shared__ float red[256];
  a[j] = ain[bb * 256 + j];
  __syncthreads();
  float acc = pab1[j];
  for (int k = 0; k < 256; k++) acc += a[k] * paw1[k * 256 + j];
  hbuf[j] = eluf_(acc);
  __syncthreads();
  float g1 = pab2[j], g2 = pab2[256 + j];
  for (int k = 0; k < 256; k++) { float hv = hbuf[k]; g1 += hv * paw2[k * 512 + j]; g2 += hv * paw2[k * 512 + 256 + j]; }
  float s = g1 * sigmoidf_(g2) + a[j];
  float mean = block_sum256(s, red) * (1.f / 256.f);
  float d = s - mean;
  float var = block_sum256(d * d, red) * (1.f / 256.f);
  float af = d * rsqrtf(var + 1e-5f) * palg[j] + palb[j];
  __syncthreads();
  a[j] = af;
  __syncthreads();
  float hh[4];
  #pragma unroll
  for (int q = 0; q < 4; q++) {
    int jj = j + q * 256;
    float ac = fgb1[jj];
    for (int k = 0; k < 256; k++) ac += a[k] * fgw1[k * 1024 + jj];
    hh[q] = eluf_(ac);
  }
  __syncthreads();
  #pragma unroll
  for (int q = 0; q < 4; q++) hbuf[j + q * 256] = hh[q];
  __syncthreads();
  float G1 = fgb2[j], G2 = fgb2[256 + j];
  for (int k = 0; k < 1024; k++) { float hv = hbuf[k]; G1 += hv * fgw2[k * 512 + j]; G2 += hv * fgw2[k * 512 + 256 + j]; }
  float s2 = G1 * sigmoidf_(G2) + a[j];
  mean = block_sum256(s2, red) * (1.f / 256.f);
  d = s2 - mean;
  var = block_sum256(d * d, red) * (1.f / 256.f);
  out[bb * 256 + j] = d * rsqrtf(var + 1e-5f) * fglg[j] + fglb[j];
}

extern "C" void kernel_launch(void* const* d_in, const int* in_sizes, int n_in,
                              void* d_out, int out_size, void* d_ws, size_t ws_size,
                              hipStream_t stream) {
  const float* x          = (const float*)d_in[0];
  const float* emb_w      = (const float*)d_in[1];
  const float* emb_b      = (const float*)d_in[2];
  const float* vg_fc1_w   = (const float*)d_in[3];
  const float* vg_fc1_b   = (const float*)d_in[4];
  const float* vg_fc2_w   = (const float*)d_in[5];
  const float* vg_fc2_b   = (const float*)d_in[6];
  const float* vg_ln_g    = (const float*)d_in[7];
  const float* vg_ln_b    = (const float*)d_in[8];
  const float* sel_fc1_w  = (const float*)d_in[9];
  const float* sel_fc1_b  = (const float*)d_in[10];
  const float* sel_fc2_w  = (const float*)d_in[11];
  const float* sel_fc2_b  = (const float*)d_in[12];
  const float* sel_skip_w = (const float*)d_in[13];
  const float* sel_skip_b = (const float*)d_in[14];
  const float* sel_ln_g   = (const float*)d_in[15];
  const float* sel_ln_b   = (const float*)d_in[16];
  const float* lstm_wih   = (const float*)d_in[17];
  const float* lstm_whh   = (const float*)d_in[18];
  const float* lstm_bih   = (const float*)d_in[19];
  const float* lstm_bhh   = (const float*)d_in[20];
  const float* pl_fc1_w   = (const float*)d_in[21];
  const float* pl_fc1_b   = (const float*)d_in[22];
  const float* pl_fc2_w   = (const float*)d_in[23];
  const float* pl_fc2_b   = (const float*)d_in[24];
  const float* pl_ln_g    = (const float*)d_in[25];
  const float* pl_ln_b    = (const float*)d_in[26];
  const float* attn_in_w  = (const float*)d_in[27];
  const float* attn_in_b  = (const float*)d_in[28];
  const float* attn_out_w = (const float*)d_in[29];
  const float* attn_out_b = (const float*)d_in[30];
  const float* attn_ln_g  = (const float*)d_in[31];
  const float* attn_ln_b  = (const float*)d_in[32];
  const float* pa_fc1_w   = (const float*)d_in[33];
  const float* pa_fc1_b   = (const float*)d_in[34];
  const float* pa_fc2_w   = (const float*)d_in[35];
  const float* pa_fc2_b   = (const float*)d_in[36];
  const float* pa_ln_g    = (const float*)d_in[37];
  const float* pa_ln_b    = (const float*)d_in[38];
  const float* fg_fc1_w   = (const float*)d_in[39];
  const float* fg_fc1_b   = (const float*)d_in[40];
  const float* fg_fc2_w   = (const float*)d_in[41];
  const float* fg_fc2_b   = (const float*)d_in[42];
  const float* fg_ln_g    = (const float*)d_in[43];
  const float* fg_ln_b    = (const float*)d_in[44];
  (void)in_sizes; (void)n_in; (void)out_size; (void)ws_size;

  float* out     = (float*)d_out;
  float* out_wts = out + BB * DD;

  // ---- workspace layout ----
  char* p = (char*)d_ws;
  ushort* wt_sel_fc1  = (ushort*)p;                 p += 1048576 * 2;
  ushort* wt_sel_skip = (ushort*)p;                 p += 65536 * 2;
  ushort* wt_sel_fc2  = (ushort*)p;                 p += 8192 * 2;
  ushort* wt_var_fc1  = (ushort*)p;                 p += 1048576 * 2;
  ushort* wt_var_fc2  = (ushort*)p;                 p += 2097152 * 2;
  ushort* wt_wih      = (ushort*)p;                 p += 524288 * 2;
  unsigned char* wt_whh_pk8 = (unsigned char*)p;    p += 524288;
  ushort* wt_pl_fc1   = (ushort*)p;                 p += 65536 * 2;
  ushort* wt_pl_fc2   = (ushort*)p;                 p += 131072 * 2;
  ushort* wt_attn     = (ushort*)p;                 p += 196608 * 2;
  ushort* selH        = (ushort*)p;                 p += (size_t)BT * 256 * 2;
  float*  selSkip     = (float*)p;                  p += (size_t)BT * 16 * 4;
  float*  selG        = (float*)p;                  p += (size_t)BT * 32 * 4;
  float*  vsn         = (float*)p;                  p += (size_t)BT * 256 * 4;
  float*  hseq1       = (float*)p;                  p += (size_t)BT * 256 * 4;
  float*  hseq2       = (float*)p;                  p += (size_t)BT * 256 * 4;
  float*  cbias       = (float*)p;                  p += 4096 * 4;
  float*  attnO       = (float*)p;                  p += 8192 * 4;
  float*  attnLN      = (float*)p;                  p += 8192 * 4;
  char*   R           = p;
  ushort* bufA16 = (ushort*)R;
  ushort* bufG16 = (ushort*)(R + (((size_t)32) << 20));
  ushort* xi16   = (ushort*)R;                               // [BT,1024] bf16 = 32 MB
  ushort* plH    = (ushort*)(R + (((size_t)16) << 20));
  ushort* plG    = (ushort*)(R + (((size_t)24) << 20));
  float*  lstmF  = (float*)(R + (((size_t)48) << 20));
  float*  qkv    = (float*)R;

  dim3 blk(256);

  // ---- weight prep ----
  wtT_k<<<dim3(8, 128, 1),  blk, 0, stream>>>(sel_fc1_w,  wt_sel_fc1,  4096, 256, 0, 0);
  wtT_k<<<dim3(1, 128, 1),  blk, 0, stream>>>(sel_skip_w, wt_sel_skip, 4096, 16,  0, 0);
  wtT_k<<<dim3(1, 8, 1),    blk, 0, stream>>>(sel_fc2_w,  wt_sel_fc2,  256,  32,  0, 0);
  wtT_k<<<dim3(8, 8, 16),   blk, 0, stream>>>(vg_fc1_w,   wt_var_fc1,  256,  256, 65536, 65536);
  wtT_k<<<dim3(16, 8, 16),  blk, 0, stream>>>(vg_fc2_w,   wt_var_fc2,  256,  512, 131072, 131072);
  wtT_k<<<dim3(8, 8, 1),    blk, 0, stream>>>(pl_fc1_w,   wt_pl_fc1,   256,  256, 0, 0);
  wtT_k<<<dim3(16, 8, 1),   blk, 0, stream>>>(pl_fc2_w,   wt_pl_fc2,   256,  512, 0, 0);
  cvt_k<<<2048, blk, 0, stream>>>(lstm_wih,  wt_wih, 524288);
  whh_pack8_k<<<64, blk, 0, stream>>>(lstm_whh, wt_whh_pk8);
  cvt_k<<<768,  blk, 0, stream>>>(attn_in_w, wt_attn, 196608);
  add2_k<<<8, blk, 0, stream>>>(lstm_bih, lstm_bhh, cbias, 4096);

  // ---- selection GRN -> softmax weights ----
  mgemm_k<2,1,1><<<dim3(2, 128, 1), blk, 0, stream>>>(x, 16, 0, wt_sel_fc1, 0, sel_fc1_b, 0,
      selH, 256, 0, 4096, 256, emb_w, emb_b, 0);
  mgemm_k<2,0,0><<<dim3(1, 128, 1), blk, 0, stream>>>(x, 16, 0, wt_sel_skip, 0, sel_skip_b, 0,
      selSkip, 16, 0, 4096, 16, emb_w, emb_b, 0);
  mgemm_k<1,0,0><<<dim3(1, 128, 1), blk, 0, stream>>>(selH, 256, 0, wt_sel_fc2, 0, sel_fc2_b, 0,
      selG, 32, 0, 256, 32, nullptr, nullptr, 0);
  sel_finish_k<<<64, blk, 0, stream>>>(selG, selSkip, sel_ln_g, sel_ln_b, out_wts, BT);

  // ---- per-variable GRNs (groups of 4) + weighted sum into vsn ----
  for (int g = 0; g < 4; g++) {
    mgemm_k<2,1,1><<<dim3(2, 128, 4), blk, 0, stream>>>(x, 16, 0,
        wt_var_fc1 + (size_t)g * 4 * 65536, 65536, vg_fc1_b + g * 1024, 256,
        bufA16, 256, (long)BT * 256, 256, 256, emb_w + g * 1024, emb_b + g * 1024, g * 4);
    mgemm_k<1,0,1><<<dim3(4, 128, 4), blk, 0, stream>>>(bufA16, 256, (long)BT * 256,
        wt_var_fc2 + (size_t)g * 4 * 131072, 131072, vg_fc2_b + g * 2048, 512,
        bufG16, 512, (long)BT * 512, 256, 512, nullptr, nullptr, 0);
    var_epi4_k<<<BT, blk, 0, stream>>>(bufG16, x, g * 4, emb_w + g * 1024, emb_b + g * 1024,
        vg_ln_g + g * 1024, vg_ln_b + g * 1024, out_wts, vsn, g == 0 ? 1 : 0);
  }

  // ---- LSTM (2 layers), xi in bf16 ----
  mgemm_k<0,0,1><<<dim3(8, 128, 1), blk, 0, stream>>>(vsn, 256, 0, wt_wih, 0, cbias, 0,
      xi16, 1024, 0, 256, 1024, nullptr, nullptr, 0);
  lstm_recur_k<<<32, 512, 0, stream>>>(xi16, wt_whh_pk8, hseq1, TT);
  mgemm_k<0,0,1><<<dim3(8, 128, 1), blk, 0, stream>>>(hseq1, 256, 0, wt_wih + 1024 * 256, 0,
      cbias + 1024, 0, xi16, 1024, 0, 256, 1024, nullptr, nullptr, 0);
  lstm_recur_k<<<32, 512, 0, stream>>>(xi16, wt_whh_pk8 + 262144, hseq2, TT);

  // ---- post-LSTM gated residual (pl GRN); skip = hseq2 + vsn fused ----
  mgemm_k<3,1,1><<<dim3(2, 128, 1), blk, 0, stream>>>(hseq2, 256, 0, wt_pl_fc1, 0, pl_fc1_b, 0,
      plH, 256, 0, 256, 256, vsn, nullptr, 0);
  mgemm_k<1,0,1><<<dim3(4, 128, 1), blk, 0, stream>>>(plH, 256, 0, wt_pl_fc2, 0, pl_fc2_b, 0,
      plG, 512, 0, 256, 512, nullptr, nullptr, 0);
  grn_epi_k<<<BT, blk, 0, stream>>>(plG, hseq2, vsn, pl_ln_g, pl_ln_b, lstmF);

  // ---- attention (decode at t=T-1 only) ----
  mgemm_k<0,0,0><<<dim3(6, 128, 1), blk, 0, stream>>>(lstmF, 256, 0, wt_attn, 0, attn_in_b, 0,
      qkv, 768, 0, 256, 768, nullptr, nullptr, 0);
  attn_decode_k<<<BB * 4, blk, 0, stream>>>(qkv, attnO, TT);
  attn_proj_ln_k<<<BB, blk, 0, stream>>>(attnO, attn_out_w, attn_out_b, lstmF,
                                         attn_ln_g, attn_ln_b, attnLN, TT);

  // ---- pa GRN + fg GRN (t=T-1 only) -> first output slice ----
  final_grns_k<<<BB, blk, 0, stream>>>(attnLN,
      pa_fc1_w, pa_fc1_b, pa_fc2_w, pa_fc2_b, pa_ln_g, pa_ln_b,
      fg_fc1_w, fg_fc1_b, fg_fc2_w, fg_fc2_b, fg_ln_g, fg_ln_b,
      out);
}

// Round 10
// 2424.548 us; speedup vs baseline: 1.0483x; 1.0483x over previous
//
#include <hip/hip_runtime.h>
#include <hip/hip_bf16.h>
#include <hip/hip_fp8.h>
#include <math.h>

// TFT: B=32, T=512, V=16, D=256, H=4, L=2.  BT = 16384.
// Round 10: revert bf16-xi (R9 regression: LSTM is chain-bound, not fetch-bound).
// LSTM core = R8 exact: 32 blocks x 512 thr, K=128 scaled fp8 MFMA, weights in
// regs, fp32 xi prefetched to registers, hout buffered 8 steps.
// Kept from R9: add2 fused into mgemm (ADT=3) + grn_epi dual-skip, one-pass LN.

#define BT 16384
#define TT 512
#define BB 32
#define VV 16
#define DD 256

typedef unsigned short ushort;
typedef unsigned int uint;
typedef unsigned long ulong_;
typedef __attribute__((ext_vector_type(8))) short short8;
typedef __attribute__((ext_vector_type(8))) unsigned short ushort8v;
typedef __attribute__((ext_vector_type(4))) float floatx4;
typedef __attribute__((ext_vector_type(8))) int int8v;

#if __has_builtin(__builtin_amdgcn_cvt_pk_fp8_f32)
#define HW_FP8_CVT 1
#endif

__device__ __forceinline__ float sigmoidf_(float x) { return 1.f / (1.f + expf(-x)); }
__device__ __forceinline__ float eluf_(float x)     { return x > 0.f ? x : expm1f(x); }
__device__ __forceinline__ float fsig(float x) {
  return __builtin_amdgcn_rcpf(1.f + __expf(-x));
}
__device__ __forceinline__ float ftanh(float x) {
  float xc = fminf(fmaxf(x, -44.f), 44.f);
  float e = __expf(-2.f * xc);
  return (1.f - e) * __builtin_amdgcn_rcpf(1.f + e);
}
__device__ __forceinline__ ushort f2bf(float f) {
  unsigned int u = __float_as_uint(f);
  unsigned int r = u + 0x7fffu + ((u >> 16) & 1u);
  return (ushort)(r >> 16);
}
__device__ __forceinline__ float bf2f(ushort b) { return __uint_as_float(((unsigned int)b) << 16); }

// dual block-wide sum over 256 threads (one shuffle pass, one barrier pair)
__device__ __forceinline__ float2 bsum256x2(float a, float b, float* red8) {
  #pragma unroll
  for (int m = 32; m > 0; m >>= 1) { a += __shfl_xor(a, m, 64); b += __shfl_xor(b, m, 64); }
  int w = threadIdx.x >> 6;
  if ((threadIdx.x & 63) == 0) { red8[w * 2] = a; red8[w * 2 + 1] = b; }
  __syncthreads();
  float ra = red8[0] + red8[2] + red8[4] + red8[6];
  float rb = red8[1] + red8[3] + red8[5] + red8[7];
  __syncthreads();
  return make_float2(ra, rb);
}

__device__ __forceinline__ float block_sum256(float v, float* red) {
  int j = threadIdx.x;
  red[j] = v; __syncthreads();
  #pragma unroll
  for (int st = 128; st > 0; st >>= 1) {
    if (j < st) red[j] += red[j + st];
    __syncthreads();
  }
  float r = red[0];
  __syncthreads();
  return r;
}

// ---------------- weight prep ----------------
__global__ void wtT_k(const float* __restrict__ src, ushort* __restrict__ dst,
                      int K, int N, long sStride, long dStride) {
  int b = blockIdx.z;
  src += (size_t)b * sStride; dst += (size_t)b * dStride;
  __shared__ float t[32][33];
  int k0 = blockIdx.y * 32, n0 = blockIdx.x * 32;
  int tx = threadIdx.x & 31, ty = threadIdx.x >> 5;
  #pragma unroll
  for (int i = 0; i < 32; i += 8) {
    int k = k0 + ty + i, n = n0 + tx;
    t[ty + i][tx] = (k < K && n < N) ? src[(size_t)k * N + n] : 0.f;
  }
  __syncthreads();
  #pragma unroll
  for (int i = 0; i < 32; i += 8) {
    int n = n0 + ty + i, k = k0 + tx;
    if (n < N && k < K) dst[(size_t)n * K + k] = f2bf(t[tx][ty + i]);
  }
}

__global__ void cvt_k(const float* __restrict__ src, ushort* __restrict__ dst, int n) {
  int i = blockIdx.x * 256 + threadIdx.x;
  if (i < n) dst[i] = f2bf(src[i]);
}

// pack whh fp32 [2][1024][256] -> fp8 e4m3 (x64) in K=128 B-frag order.
__global__ void whh_pack8_k(const float* __restrict__ whh, unsigned char* __restrict__ dst) {
  int gid = blockIdx.x * 256 + threadIdx.x;   // 16384 total
  int layer = gid >> 13;
  int rem = gid & 8191;
  int lane = rem & 63;
  int f = (rem >> 6) & 15;
  int wave = rem >> 10;
  int kt2 = f & 1, ts = (f >> 1) & 1, g = f >> 2;
  int n = g * 256 + wave * 32 + ts * 16 + (lane & 15);
  int k0 = kt2 * 128 + (lane >> 4) * 32;
  const float* src = whh + (size_t)layer * 262144 + (size_t)n * 256 + k0;
  unsigned char* d = dst + (size_t)gid * 32;
  #pragma unroll
  for (int b = 0; b < 32; b++) {
    __hip_fp8_e4m3 q(src[b] * 64.f);
    d[b] = q.__x;
  }
}

// ---------------- bf16 MFMA GEMM ----------------
// ADT: 0 A fp32; 1 A bf16; 2 embedded-on-the-fly; 3 A = A1+A2 fp32 (A2 via embw)
template<int ADT, int ACT, int CDT>
__global__ __launch_bounds__(256) void mgemm_k(
    const void* __restrict__ Aall, int lda, long aStride,
    const ushort* __restrict__ Ball, long bStride,
    const float* __restrict__ biasAll, long biasStride,
    void* __restrict__ Call, int ldc, long cStride,
    int K, int Nvalid,
    const float* __restrict__ embw, const float* __restrict__ embb, int xbase) {
  int z = blockIdx.z;
  const ushort* B = Ball + (size_t)z * bStride;
  const float* bias = biasAll ? biasAll + (size_t)z * biasStride : nullptr;
  int m0 = blockIdx.y * 128, n0 = blockIdx.x * 128;
  __shared__ ushort As[128][40];
  __shared__ ushort Bs[128][40];
  int tid = threadIdx.x;
  int r = tid >> 1, half = tid & 1;
  int wave = tid >> 6, lane = tid & 63;
  int wm = (wave >> 1) * 64, wn = (wave & 1) * 64;
  int lm = lane & 15, lq = lane >> 4;
  floatx4 acc[4][4];
  #pragma unroll
  for (int i = 0; i < 4; i++)
    #pragma unroll
    for (int j = 0; j < 4; j++) acc[i][j] = (floatx4)0.f;

  for (int k0 = 0; k0 < K; k0 += 32) {
    int kk = k0 + half * 16;
    {
      int gm = m0 + r;
      ushort tmp[16];
      if (ADT == 0) {
        const float* Af = (const float*)Aall + (size_t)z * aStride + (size_t)gm * lda + kk;
        #pragma unroll
        for (int q = 0; q < 4; q++) {
          float4 f = ((const float4*)Af)[q];
          tmp[q * 4 + 0] = f2bf(f.x); tmp[q * 4 + 1] = f2bf(f.y);
          tmp[q * 4 + 2] = f2bf(f.z); tmp[q * 4 + 3] = f2bf(f.w);
        }
      } else if (ADT == 1) {
        const ushort* Ab = (const ushort*)Aall + (size_t)z * aStride + (size_t)gm * lda + kk;
        *(ushort8v*)&tmp[0] = *(const ushort8v*)(Ab);
        *(ushort8v*)&tmp[8] = *(const ushort8v*)(Ab + 8);
      } else if (ADT == 2) {
        const float* xp = (const float*)Aall;
        float xv = xp[(size_t)gm * lda + xbase + z + (kk >> 8)];
        const float4* ew = (const float4*)(embw + (size_t)z * 256 + kk);
        const float4* eb = (const float4*)(embb + (size_t)z * 256 + kk);
        #pragma unroll
        for (int q = 0; q < 4; q++) {
          float4 w4 = ew[q], b4 = eb[q];
          tmp[q * 4 + 0] = f2bf(xv * w4.x + b4.x); tmp[q * 4 + 1] = f2bf(xv * w4.y + b4.y);
          tmp[q * 4 + 2] = f2bf(xv * w4.z + b4.z); tmp[q * 4 + 3] = f2bf(xv * w4.w + b4.w);
        }
      } else {
        const float* A1 = (const float*)Aall + (size_t)z * aStride + (size_t)gm * lda + kk;
        const float* A2 = embw + (size_t)z * aStride + (size_t)gm * lda + kk;
        #pragma unroll
        for (int q = 0; q < 4; q++) {
          float4 f1 = ((const float4*)A1)[q];
          float4 f2 = ((const float4*)A2)[q];
          tmp[q * 4 + 0] = f2bf(f1.x + f2.x); tmp[q * 4 + 1] = f2bf(f1.y + f2.y);
          tmp[q * 4 + 2] = f2bf(f1.z + f2.z); tmp[q * 4 + 3] = f2bf(f1.w + f2.w);
        }
      }
      *(ushort8v*)&As[r][half * 16]     = *(ushort8v*)&tmp[0];
      *(ushort8v*)&As[r][half * 16 + 8] = *(ushort8v*)&tmp[8];
    }
    {
      int gn = n0 + r;
      ushort tmp[16];
      if (gn < Nvalid) {
        const ushort* Bp = B + (size_t)gn * K + kk;
        *(ushort8v*)&tmp[0] = *(const ushort8v*)(Bp);
        *(ushort8v*)&tmp[8] = *(const ushort8v*)(Bp + 8);
      } else {
        #pragma unroll
        for (int q = 0; q < 16; q++) tmp[q] = 0;
      }
      *(ushort8v*)&Bs[r][half * 16]     = *(ushort8v*)&tmp[0];
      *(ushort8v*)&Bs[r][half * 16 + 8] = *(ushort8v*)&tmp[8];
    }
    __syncthreads();
    short8 fa[4], fb[4];
    #pragma unroll
    for (int i = 0; i < 4; i++) fa[i] = *(const short8*)&As[wm + i * 16 + lm][lq * 8];
    #pragma unroll
    for (int j = 0; j < 4; j++) fb[j] = *(const short8*)&Bs[wn + j * 16 + lm][lq * 8];
    #pragma unroll
    for (int i = 0; i < 4; i++)
      #pragma unroll
      for (int j = 0; j < 4; j++)
        acc[i][j] = __builtin_amdgcn_mfma_f32_16x16x32_bf16(fa[i], fb[j], acc[i][j], 0, 0, 0);
    __syncthreads();
  }
  #pragma unroll
  for (int j = 0; j < 4; j++) {
    int gn = n0 + wn + j * 16 + lm;
    if (gn >= Nvalid) continue;
    float bv = bias ? bias[gn] : 0.f;
    #pragma unroll
    for (int i = 0; i < 4; i++) {
      #pragma unroll
      for (int rg = 0; rg < 4; rg++) {
        int gm = m0 + wm + i * 16 + lq * 4 + rg;
        float v = acc[i][j][rg] + bv;
        if (ACT == 1) v = eluf_(v);
        if (CDT == 0) ((float*)Call + (size_t)z * cStride)[(size_t)gm * ldc + gn] = v;
        else ((ushort*)Call + (size_t)z * cStride)[(size_t)gm * ldc + gn] = f2bf(v);
      }
    }
  }
}

// ---------------- selection GRN finish ----------------
__global__ void sel_finish_k(const float* __restrict__ selG, const float* __restrict__ selSkip,
                             const float* __restrict__ lng, const float* __restrict__ lnb,
                             float* __restrict__ wout, int M) {
  int m = blockIdx.x * 256 + threadIdx.x;
  if (m >= M) return;
  float s[16];
  float mean = 0.f;
  #pragma unroll
  for (int i = 0; i < 16; i++) {
    float h1 = selG[m * 32 + i], h2 = selG[m * 32 + 16 + i];
    float val = h1 * sigmoidf_(h2) + selSkip[m * 16 + i];
    s[i] = val; mean += val;
  }
  mean *= (1.f / 16.f);
  float var = 0.f;
  #pragma unroll
  for (int i = 0; i < 16; i++) { float d = s[i] - mean; var += d * d; }
  var *= (1.f / 16.f);
  float inv = rsqrtf(var + 1e-5f);
  float mx = -1e30f;
  #pragma unroll
  for (int i = 0; i < 16; i++) { s[i] = (s[i] - mean) * inv * lng[i] + lnb[i]; mx = fmaxf(mx, s[i]); }
  float sum = 0.f;
  #pragma unroll
  for (int i = 0; i < 16; i++) { s[i] = expf(s[i] - mx); sum += s[i]; }
  float isum = 1.f / sum;
  #pragma unroll
  for (int i = 0; i < 16; i++) wout[m * 16 + i] = s[i] * isum;
}

// ---------------- var-GRN epilogue, 4 variables per launch, one-pass LN ----------------
__global__ __launch_bounds__(256) void var_epi4_k(
    const ushort* __restrict__ G16,
    const float* __restrict__ x, int vbase,
    const float* __restrict__ embw, const float* __restrict__ embb,
    const float* __restrict__ lng, const float* __restrict__ lnb,
    const float* __restrict__ wts, float* __restrict__ vsn, int first) {
  int m = blockIdx.x, j = threadIdx.x;
  __shared__ float red8[8];
  float accv = 0.f;
  #pragma unroll
  for (int z = 0; z < 4; z++) {
    int v = vbase + z;
    const ushort* Gp = G16 + ((size_t)z * BT + m) * 512;
    float g1 = bf2f(Gp[j]), g2 = bf2f(Gp[256 + j]);
    float e = x[m * VV + v] * embw[z * 256 + j] + embb[z * 256 + j];
    float s = g1 * sigmoidf_(g2) + e;
    float2 r = bsum256x2(s, s * s, red8);
    float mean = r.x * (1.f / 256.f);
    float var = r.y * (1.f / 256.f) - mean * mean;
    float o = (s - mean) * rsqrtf(var + 1e-5f) * lng[z * 256 + j] + lnb[z * 256 + j];
    accv += wts[m * VV + v] * o;
  }
  size_t oi = (size_t)m * 256 + j;
  if (first) vsn[oi] = accv; else vsn[oi] += accv;
}

// ---------------- generic GRN epilogue: GLU + (skipA+skipB) + LN, one-pass ----------------
__global__ __launch_bounds__(256) void grn_epi_k(
    const ushort* __restrict__ G, const float* __restrict__ skipA,
    const float* __restrict__ skipB,
    const float* __restrict__ lng, const float* __restrict__ lnb,
    float* __restrict__ out) {
  int m = blockIdx.x, j = threadIdx.x;
  __shared__ float red8[8];
  float g1 = bf2f(G[(size_t)m * 512 + j]), g2 = bf2f(G[(size_t)m * 512 + 256 + j]);
  float sk = skipA[(size_t)m * 256 + j];
  if (skipB) sk += skipB[(size_t)m * 256 + j];
  float s = g1 * sigmoidf_(g2) + sk;
  float2 r = bsum256x2(s, s * s, red8);
  float mean = r.x * (1.f / 256.f);
  float var = r.y * (1.f / 256.f) - mean * mean;
  out[(size_t)m * 256 + j] = (s - mean) * rsqrtf(var + 1e-5f) * lng[j] + lnb[j];
}

// ---------------- elementwise ----------------
__global__ void add2_k(const float* __restrict__ a, const float* __restrict__ b,
                       float* __restrict__ c, int n) {
  int i = blockIdx.x * 256 + threadIdx.x;
  if (i < n) c[i] = a[i] + b[i];
}

// ---------------- LSTM recurrence: K=128 scaled fp8 MFMA (R8 exact core) ----------------
#define DESC (1.f / 1024.f)
#define H8S 272
__global__ __launch_bounds__(512, 2) void lstm_recur_k(
    const float* __restrict__ xi,            // [B,T,1024] = xW^T + bih + bhh
    const unsigned char* __restrict__ wpk,   // fp8 K128-frag-packed layer (262144 B)
    float* __restrict__ hout,                // [B,T,256]
    int T) {
  int bb = blockIdx.x;                        // one batch
  int tid = threadIdx.x;
  int wave = tid >> 6, lane = tid & 63;
  int lm = lane & 15, lq = lane >> 4;
  __shared__ __align__(16) unsigned char h8[2][16 * H8S];
  for (int i = tid; i < 2 * 16 * H8S / 4; i += 512) ((uint*)h8)[i] = 0;

  int8v wr[16];
  {
    const int8v* wp = (const int8v*)wpk;
    #pragma unroll
    for (int f = 0; f < 16; f++) wr[f] = wp[(wave * 16 + f) * 64 + lane];
  }
  bool act = (lq == 0);
  int jj = wave * 32 + lm;                   // ts adds +16
  const float* xg = xi + (size_t)bb * T * 1024;
  float xq[8], xn[8];
  if (act) {
    #pragma unroll
    for (int g = 0; g < 4; g++) {
      xq[2 * g]     = xg[g * 256 + jj];
      xq[2 * g + 1] = xg[g * 256 + jj + 16];
    }
  }
  float cst[2] = {0.f, 0.f};
  float hbf[2][8];
  int arow = lm * H8S + lq * 32;
  __syncthreads();

  for (int t = 0; t < T; t++) {
    int cur = t & 1, nxt = cur ^ 1;
    if (act && t + 1 < T) {
      const float* xp = xg + (size_t)(t + 1) * 1024;
      #pragma unroll
      for (int g = 0; g < 4; g++) {
        xn[2 * g]     = xp[g * 256 + jj];
        xn[2 * g + 1] = xp[g * 256 + jj + 16];
      }
    }
    int8v a[2];
    #pragma unroll
    for (int kt = 0; kt < 2; kt++)
      a[kt] = *(const int8v*)&h8[cur][arow + kt * 128];
    floatx4 acc[8];                 // f = g*2 + ts
    #pragma unroll
    for (int f = 0; f < 8; f++) acc[f] = (floatx4)0.f;
    #pragma unroll
    for (int kt = 0; kt < 2; kt++)
      #pragma unroll
      for (int f = 0; f < 8; f++)
        acc[f] = __builtin_amdgcn_mfma_scale_f32_16x16x128_f8f6f4(
            a[kt], wr[f * 2 + kt], acc[f], 0, 0, 0, 0x7f7f7f7f, 0, 0x7f7f7f7f);
    if (act) {
      int tb = t & 7;
      #pragma unroll
      for (int ts = 0; ts < 2; ts++) {
        float pi = acc[0 + ts][0] * DESC + xq[0 + ts];
        float pf = acc[2 + ts][0] * DESC + xq[2 + ts];
        float pg = acc[4 + ts][0] * DESC + xq[4 + ts];
        float po = acc[6 + ts][0] * DESC + xq[6 + ts];
        float c = fsig(pf) * cst[ts] + fsig(pi) * ftanh(pg);
        cst[ts] = c;
        hbf[ts][tb] = fsig(po) * ftanh(c);
      }
#ifdef HW_FP8_CVT
      int pk = __builtin_amdgcn_cvt_pk_fp8_f32(hbf[0][tb] * 16.f, hbf[1][tb] * 16.f, 0, false);
      h8[nxt][jj]      = (unsigned char)(pk & 0xff);
      h8[nxt][jj + 16] = (unsigned char)((pk >> 8) & 0xff);
#else
      __hip_fp8_e4m3 q0(hbf[0][tb] * 16.f), q1(hbf[1][tb] * 16.f);
      h8[nxt][jj]      = q0.__x;
      h8[nxt][jj + 16] = q1.__x;
#endif
      if (tb == 7) {
        #pragma unroll
        for (int q = 0; q < 8; q++) {
          size_t base = ((size_t)(bb * T + t - 7 + q)) * 256;
          hout[base + jj]      = hbf[0][q];
          hout[base + jj + 16] = hbf[1][q];
        }
      }
      #pragma unroll
      for (int g = 0; g < 8; g++) xq[g] = xn[g];
    }
    __syncthreads();
  }
}

// ---------------- attention, decode-style (only query t = T-1) ----------------
__global__ __launch_bounds__(256) void attn_decode_k(const float* __restrict__ qkv,
                                                     float* __restrict__ o, int T) {
  int bh = blockIdx.x; int b = bh >> 2, h = bh & 3;
  int tid = threadIdx.x;
  __shared__ float q[64];
  __shared__ float p[512];
  __shared__ float red[256];
  if (tid < 64) q[tid] = qkv[((size_t)(b * T + T - 1)) * 768 + h * 64 + tid];
  __syncthreads();
  for (int t = tid; t < 512; t += 256) {
    const float* kv = qkv + ((size_t)(b * T + t)) * 768 + 256 + h * 64;
    float s = 0.f;
    #pragma unroll 16
    for (int d = 0; d < 64; d++) s += q[d] * kv[d];
    p[t] = s * 0.125f;
  }
  __syncthreads();
  red[tid] = fmaxf(p[tid], p[tid + 256]); __syncthreads();
  for (int st = 128; st > 0; st >>= 1) { if (tid < st) red[tid] = fmaxf(red[tid], red[tid + st]); __syncthreads(); }
  float mx = red[0]; __syncthreads();
  float e0 = expf(p[tid] - mx), e1 = expf(p[tid + 256] - mx);
  red[tid] = e0 + e1; __syncthreads();
  for (int st = 128; st > 0; st >>= 1) { if (tid < st) red[tid] += red[tid + st]; __syncthreads(); }
  float inv = 1.f / red[0];
  __syncthreads();
  p[tid] = e0; p[tid + 256] = e1;
  __syncthreads();
  int d = tid & 63, grp = tid >> 6;
  float acc = 0.f;
  for (int t = grp * 128; t < grp * 128 + 128; t++)
    acc += p[t] * qkv[((size_t)(b * T + t)) * 768 + 512 + h * 64 + d];
  red[tid] = acc; __syncthreads();
  if (grp == 0)
    o[(b * 4 + h) * 64 + d] = (red[tid] + red[tid + 64] + red[tid + 128] + red[tid + 192]) * inv;
}

// ---------------- attn out-proj + residual + LN (only t=T-1) ----------------
__global__ __launch_bounds__(256) void attn_proj_ln_k(
    const float* __restrict__ attnO, const float* __restrict__ W, const float* __restrict__ bias,
    const float* __restrict__ lstmF, const float* __restrict__ lng, const float* __restrict__ lnb,
    float* __restrict__ out, int T) {
  int bb = blockIdx.x, j = threadIdx.x;
  __shared__ float a[256];
  __shared__ float red[256];
  a[j] = attnO[bb * 256 + j];
  __syncthreads();
  float acc = bias[j];
  const float* wr = W + (size_t)j * 256;
  #pragma unroll 8
  for (int k = 0; k < 256; k += 4) {
    float4 w4 = *(const float4*)(wr + k);
    acc += a[k] * w4.x + a[k + 1] * w4.y + a[k + 2] * w4.z + a[k + 3] * w4.w;
  }
  float s = acc + lstmF[((size_t)(bb * T + T - 1)) * 256 + j];
  float mean = block_sum256(s, red) * (1.f / 256.f);
  float d = s - mean;
  float var = block_sum256(d * d, red) * (1.f / 256.f);
  out[bb * 256 + j] = d * rsqrtf(var + 1e-5f) * lng[j] + lnb[j];
}

// ---------------- final two GRNs (pa then fg), only t=T-1 ----------------
__global__ __launch_bounds__(256) void final_grns_k(
    const float* __restrict__ ain,
    const float* __restrict__ paw1, const float* __restrict__ pab1,
    const float* __restrict__ paw2, const float* __restrict__ pab2,
    const float* __restrict__ palg, const float* __restrict__ palb,
    const float* __restrict__ fgw1, const float* __restrict__ fgb1,
    const float* __restrict__ fgw2, const float* __restrict__ fgb2,
    const float* __restrict__ fglg, const float* __restrict__ fglb,
    float* __restrict__ out) {
  int bb = blockIdx.x, j = threadIdx.x;
  __shared__ float a[256];
  __shared__ float hbuf[1024];
  __shared__ float red[256];
  a[j] = ain[bb * 256 + j];
  __syncthreads();
  float acc = pab1[j];
  for (int k = 0; k < 256; k++) acc += a[k] * paw1[k * 256 + j];
  hbuf[j] = eluf_(acc);
  __syncthreads();
  float g1 = pab2[j], g2 = pab2[256 + j];
  for (int k = 0; k < 256; k++) { float hv = hbuf[k]; g1 += hv * paw2[k * 512 + j]; g2 += hv * paw2[k * 512 + 256 + j]; }
  float s = g1 * sigmoidf_(g2) + a[j];
  float mean = block_sum256(s, red) * (1.f / 256.f);
  float d = s - mean;
  float var = block_sum256(d * d, red) * (1.f / 256.f);
  float af = d * rsqrtf(var + 1e-5f) * palg[j] + palb[j];
  __syncthreads();
  a[j] = af;
  __syncthreads();
  float hh[4];
  #pragma unroll
  for (int q = 0; q < 4; q++) {
    int jj = j + q * 256;
    float ac = fgb1[jj];
    for (int k = 0; k < 256; k++) ac += a[k] * fgw1[k * 1024 + jj];
    hh[q] = eluf_(ac);
  }
  __syncthreads();
  #pragma unroll
  for (int q = 0; q < 4; q++) hbuf[j + q * 256] = hh[q];
  __syncthreads();
  float G1 = fgb2[j], G2 = fgb2[256 + j];
  for (int k = 0; k < 1024; k++) { float hv = hbuf[k]; G1 += hv * fgw2[k * 512 + j]; G2 += hv * fgw2[k * 512 + 256 + j]; }
  float s2 = G1 * sigmoidf_(G2) + a[j];
  mean = block_sum256(s2, red) * (1.f / 256.f);
  d = s2 - mean;
  var = block_sum256(d * d, red) * (1.f / 256.f);
  out[bb * 256 + j] = d * rsqrtf(var + 1e-5f) * fglg[j] + fglb[j];
}

extern "C" void kernel_launch(void* const* d_in, const int* in_sizes, int n_in,
                              void* d_out, int out_size, void* d_ws, size_t ws_size,
                              hipStream_t stream) {
  const float* x          = (const float*)d_in[0];
  const float* emb_w      = (const float*)d_in[1];
  const float* emb_b      = (const float*)d_in[2];
  const float* vg_fc1_w   = (const float*)d_in[3];
  const float* vg_fc1_b   = (const float*)d_in[4];
  const float* vg_fc2_w   = (const float*)d_in[5];
  const float* vg_fc2_b   = (const float*)d_in[6];
  const float* vg_ln_g    = (const float*)d_in[7];
  const float* vg_ln_b    = (const float*)d_in[8];
  const float* sel_fc1_w  = (const float*)d_in[9];
  const float* sel_fc1_b  = (const float*)d_in[10];
  const float* sel_fc2_w  = (const float*)d_in[11];
  const float* sel_fc2_b  = (const float*)d_in[12];
  const float* sel_skip_w = (const float*)d_in[13];
  const float* sel_skip_b = (const float*)d_in[14];
  const float* sel_ln_g   = (const float*)d_in[15];
  const float* sel_ln_b   = (const float*)d_in[16];
  const float* lstm_wih   = (const float*)d_in[17];
  const float* lstm_whh   = (const float*)d_in[18];
  const float* lstm_bih   = (const float*)d_in[19];
  const float* lstm_bhh   = (const float*)d_in[20];
  const float* pl_fc1_w   = (const float*)d_in[21];
  const float* pl_fc1_b   = (const float*)d_in[22];
  const float* pl_fc2_w   = (const float*)d_in[23];
  const float* pl_fc2_b   = (const float*)d_in[24];
  const float* pl_ln_g    = (const float*)d_in[25];
  const float* pl_ln_b    = (const float*)d_in[26];
  const float* attn_in_w  = (const float*)d_in[27];
  const float* attn_in_b  = (const float*)d_in[28];
  const float* attn_out_w = (const float*)d_in[29];
  const float* attn_out_b = (const float*)d_in[30];
  const float* attn_ln_g  = (const float*)d_in[31];
  const float* attn_ln_b  = (const float*)d_in[32];
  const float* pa_fc1_w   = (const float*)d_in[33];
  const float* pa_fc1_b   = (const float*)d_in[34];
  const float* pa_fc2_w   = (const float*)d_in[35];
  const float* pa_fc2_b   = (const float*)d_in[36];
  const float* pa_ln_g    = (const float*)d_in[37];
  const float* pa_ln_b    = (const float*)d_in[38];
  const float* fg_fc1_w   = (const float*)d_in[39];
  const float* fg_fc1_b   = (const float*)d_in[40];
  const float* fg_fc2_w   = (const float*)d_in[41];
  const float* fg_fc2_b   = (const float*)d_in[42];
  const float* fg_ln_g    = (const float*)d_in[43];
  const float* fg_ln_b    = (const float*)d_in[44];
  (void)in_sizes; (void)n_in; (void)out_size; (void)ws_size;

  float* out     = (float*)d_out;
  float* out_wts = out + BB * DD;

  // ---- workspace layout ----
  char* p = (char*)d_ws;
  ushort* wt_sel_fc1  = (ushort*)p;                 p += 1048576 * 2;
  ushort* wt_sel_skip = (ushort*)p;                 p += 65536 * 2;
  ushort* wt_sel_fc2  = (ushort*)p;                 p += 8192 * 2;
  ushort* wt_var_fc1  = (ushort*)p;                 p += 1048576 * 2;
  ushort* wt_var_fc2  = (ushort*)p;                 p += 2097152 * 2;
  ushort* wt_wih      = (ushort*)p;                 p += 524288 * 2;
  unsigned char* wt_whh_pk8 = (unsigned char*)p;    p += 524288;
  ushort* wt_pl_fc1   = (ushort*)p;                 p += 65536 * 2;
  ushort* wt_pl_fc2   = (ushort*)p;                 p += 131072 * 2;
  ushort* wt_attn     = (ushort*)p;                 p += 196608 * 2;
  ushort* selH        = (ushort*)p;                 p += (size_t)BT * 256 * 2;
  float*  selSkip     = (float*)p;                  p += (size_t)BT * 16 * 4;
  float*  selG        = (float*)p;                  p += (size_t)BT * 32 * 4;
  float*  vsn         = (float*)p;                  p += (size_t)BT * 256 * 4;
  float*  hseq1       = (float*)p;                  p += (size_t)BT * 256 * 4;
  float*  hseq2       = (float*)p;                  p += (size_t)BT * 256 * 4;
  float*  cbias       = (float*)p;                  p += 4096 * 4;
  float*  attnO       = (float*)p;                  p += 8192 * 4;
  float*  attnLN      = (float*)p;                  p += 8192 * 4;
  char*   R           = p;
  ushort* bufA16 = (ushort*)R;
  ushort* bufG16 = (ushort*)(R + (((size_t)32) << 20));
  float*  xi     = (float*)R;                                // [BT,1024] fp32 = 64 MB
  ushort* plH    = (ushort*)(R + (((size_t)16) << 20));
  ushort* plG    = (ushort*)(R + (((size_t)24) << 20));
  float*  lstmF  = (float*)(R + (((size_t)48) << 20));
  float*  qkv    = (float*)R;

  dim3 blk(256);

  // ---- weight prep ----
  wtT_k<<<dim3(8, 128, 1),  blk, 0, stream>>>(sel_fc1_w,  wt_sel_fc1,  4096, 256, 0, 0);
  wtT_k<<<dim3(1, 128, 1),  blk, 0, stream>>>(sel_skip_w, wt_sel_skip, 4096, 16,  0, 0);
  wtT_k<<<dim3(1, 8, 1),    blk, 0, stream>>>(sel_fc2_w,  wt_sel_fc2,  256,  32,  0, 0);
  wtT_k<<<dim3(8, 8, 16),   blk, 0, stream>>>(vg_fc1_w,   wt_var_fc1,  256,  256, 65536, 65536);
  wtT_k<<<dim3(16, 8, 16),  blk, 0, stream>>>(vg_fc2_w,   wt_var_fc2,  256,  512, 131072, 131072);
  wtT_k<<<dim3(8, 8, 1),    blk, 0, stream>>>(pl_fc1_w,   wt_pl_fc1,   256,  256, 0, 0);
  wtT_k<<<dim3(16, 8, 1),   blk, 0, stream>>>(pl_fc2_w,   wt_pl_fc2,   256,  512, 0, 0);
  cvt_k<<<2048, blk, 0, stream>>>(lstm_wih,  wt_wih, 524288);
  whh_pack8_k<<<64, blk, 0, stream>>>(lstm_whh, wt_whh_pk8);
  cvt_k<<<768,  blk, 0, stream>>>(attn_in_w, wt_attn, 196608);
  add2_k<<<8, blk, 0, stream>>>(lstm_bih, lstm_bhh, cbias, 4096);

  // ---- selection GRN -> softmax weights ----
  mgemm_k<2,1,1><<<dim3(2, 128, 1), blk, 0, stream>>>(x, 16, 0, wt_sel_fc1, 0, sel_fc1_b, 0,
      selH, 256, 0, 4096, 256, emb_w, emb_b, 0);
  mgemm_k<2,0,0><<<dim3(1, 128, 1), blk, 0, stream>>>(x, 16, 0, wt_sel_skip, 0, sel_skip_b, 0,
      selSkip, 16, 0, 4096, 16, emb_w, emb_b, 0);
  mgemm_k<1,0,0><<<dim3(1, 128, 1), blk, 0, stream>>>(selH, 256, 0, wt_sel_fc2, 0, sel_fc2_b, 0,
      selG, 32, 0, 256, 32, nullptr, nullptr, 0);
  sel_finish_k<<<64, blk, 0, stream>>>(selG, selSkip, sel_ln_g, sel_ln_b, out_wts, BT);

  // ---- per-variable GRNs (groups of 4) + weighted sum into vsn ----
  for (int g = 0; g < 4; g++) {
    mgemm_k<2,1,1><<<dim3(2, 128, 4), blk, 0, stream>>>(x, 16, 0,
        wt_var_fc1 + (size_t)g * 4 * 65536, 65536, vg_fc1_b + g * 1024, 256,
        bufA16, 256, (long)BT * 256, 256, 256, emb_w + g * 1024, emb_b + g * 1024, g * 4);
    mgemm_k<1,0,1><<<dim3(4, 128, 4), blk, 0, stream>>>(bufA16, 256, (long)BT * 256,
        wt_var_fc2 + (size_t)g * 4 * 131072, 131072, vg_fc2_b + g * 2048, 512,
        bufG16, 512, (long)BT * 512, 256, 512, nullptr, nullptr, 0);
    var_epi4_k<<<BT, blk, 0, stream>>>(bufG16, x, g * 4, emb_w + g * 1024, emb_b + g * 1024,
        vg_ln_g + g * 1024, vg_ln_b + g * 1024, out_wts, vsn, g == 0 ? 1 : 0);
  }

  // ---- LSTM (2 layers), fp32 xi ----
  mgemm_k<0,0,0><<<dim3(8, 128, 1), blk, 0, stream>>>(vsn, 256, 0, wt_wih, 0, cbias, 0,
      xi, 1024, 0, 256, 1024, nullptr, nullptr, 0);
  lstm_recur_k<<<32, 512, 0, stream>>>(xi, wt_whh_pk8, hseq1, TT);
  mgemm_k<0,0,0><<<dim3(8, 128, 1), blk, 0, stream>>>(hseq1, 256, 0, wt_wih + 1024 * 256, 0,
      cbias + 1024, 0, xi, 1024, 0, 256, 1024, nullptr, nullptr, 0);
  lstm_recur_k<<<32, 512, 0, stream>>>(xi, wt_whh_pk8 + 262144, hseq2, TT);

  // ---- post-LSTM gated residual (pl GRN); skip = hseq2 + vsn fused ----
  mgemm_k<3,1,1><<<dim3(2, 128, 1), blk, 0, stream>>>(hseq2, 256, 0, wt_pl_fc1, 0, pl_fc1_b, 0,
      plH, 256, 0, 256, 256, vsn, nullptr, 0);
  mgemm_k<1,0,1><<<dim3(4, 128, 1), blk, 0, stream>>>(plH, 256, 0, wt_pl_fc2, 0, pl_fc2_b, 0,
      plG, 512, 0, 256, 512, nullptr, nullptr, 0);
  grn_epi_k<<<BT, blk, 0, stream>>>(plG, hseq2, vsn, pl_ln_g, pl_ln_b, lstmF);

  // ---- attention (decode at t=T-1 only) ----
  mgemm_k<0,0,0><<<dim3(6, 128, 1), blk, 0, stream>>>(lstmF, 256, 0, wt_attn, 0, attn_in_b, 0,
      qkv, 768, 0, 256, 768, nullptr, nullptr, 0);
  attn_decode_k<<<BB * 4, blk, 0, stream>>>(qkv, attnO, TT);
  attn_proj_ln_k<<<BB, blk, 0, stream>>>(attnO, attn_out_w, attn_out_b, lstmF,
                                         attn_ln_g, attn_ln_b, attnLN, TT);

  // ---- pa GRN + fg GRN (t=T-1 only) -> first output slice ----
  final_grns_k<<<BB, blk, 0, stream>>>(attnLN,
      pa_fc1_w, pa_fc1_b, pa_fc2_w, pa_fc2_b, pa_ln_g, pa_ln_b,
      fg_fc1_w, fg_fc1_b, fg_fc2_w, fg_fc2_b, fg_ln_g, fg_ln_b,
      out);
}

// Round 11
// 2168.100 us; speedup vs baseline: 1.1723x; 1.1183x over previous
//
#include <hip/hip_runtime.h>
#include <hip/hip_bf16.h>
#include <hip/hip_fp8.h>
#include <math.h>

// TFT: B=32, T=512, V=16, D=256, H=4, L=2.  BT = 16384.
// Round 11: rank-1 collapse of embedded-input GEMMs.
//   embedded[m,v*256+j] = x[m,v]*embw[v,j]+embb[v,j]  (rank-1 in x per variable)
//   => sel fc1 (K=4096), sel skip (K=4096), var fc1 (x16) become tiny FMA kernels
//   using precomputed R[v][n]=Sum_j embw*W, C[v][n]=Sum_j embb*W (+bias).
// Everything else = R10 exact (best known config):
//   LSTM: 32 blocks x 512 thr, K=128 scaled fp8 MFMA, weights in regs, fp32 xi.

#define BT 16384
#define TT 512
#define BB 32
#define VV 16
#define DD 256

typedef unsigned short ushort;
typedef unsigned int uint;
typedef unsigned long ulong_;
typedef __attribute__((ext_vector_type(8))) short short8;
typedef __attribute__((ext_vector_type(8))) unsigned short ushort8v;
typedef __attribute__((ext_vector_type(4))) float floatx4;
typedef __attribute__((ext_vector_type(8))) int int8v;

#if __has_builtin(__builtin_amdgcn_cvt_pk_fp8_f32)
#define HW_FP8_CVT 1
#endif

__device__ __forceinline__ float sigmoidf_(float x) { return 1.f / (1.f + expf(-x)); }
__device__ __forceinline__ float eluf_(float x)     { return x > 0.f ? x : expm1f(x); }
__device__ __forceinline__ float fsig(float x) {
  return __builtin_amdgcn_rcpf(1.f + __expf(-x));
}
__device__ __forceinline__ float ftanh(float x) {
  float xc = fminf(fmaxf(x, -44.f), 44.f);
  float e = __expf(-2.f * xc);
  return (1.f - e) * __builtin_amdgcn_rcpf(1.f + e);
}
__device__ __forceinline__ ushort f2bf(float f) {
  unsigned int u = __float_as_uint(f);
  unsigned int r = u + 0x7fffu + ((u >> 16) & 1u);
  return (ushort)(r >> 16);
}
__device__ __forceinline__ float bf2f(ushort b) { return __uint_as_float(((unsigned int)b) << 16); }

// dual block-wide sum over 256 threads (one shuffle pass, one barrier pair)
__device__ __forceinline__ float2 bsum256x2(float a, float b, float* red8) {
  #pragma unroll
  for (int m = 32; m > 0; m >>= 1) { a += __shfl_xor(a, m, 64); b += __shfl_xor(b, m, 64); }
  int w = threadIdx.x >> 6;
  if ((threadIdx.x & 63) == 0) { red8[w * 2] = a; red8[w * 2 + 1] = b; }
  __syncthreads();
  float ra = red8[0] + red8[2] + red8[4] + red8[6];
  float rb = red8[1] + red8[3] + red8[5] + red8[7];
  __syncthreads();
  return make_float2(ra, rb);
}

__device__ __forceinline__ float block_sum256(float v, float* red) {
  int j = threadIdx.x;
  red[j] = v; __syncthreads();
  #pragma unroll
  for (int st = 128; st > 0; st >>= 1) {
    if (j < st) red[j] += red[j + st];
    __syncthreads();
  }
  float r = red[0];
  __syncthreads();
  return r;
}

// ---------------- weight prep ----------------
__global__ void wtT_k(const float* __restrict__ src, ushort* __restrict__ dst,
                      int K, int N, long sStride, long dStride) {
  int b = blockIdx.z;
  src += (size_t)b * sStride; dst += (size_t)b * dStride;
  __shared__ float t[32][33];
  int k0 = blockIdx.y * 32, n0 = blockIdx.x * 32;
  int tx = threadIdx.x & 31, ty = threadIdx.x >> 5;
  #pragma unroll
  for (int i = 0; i < 32; i += 8) {
    int k = k0 + ty + i, n = n0 + tx;
    t[ty + i][tx] = (k < K && n < N) ? src[(size_t)k * N + n] : 0.f;
  }
  __syncthreads();
  #pragma unroll
  for (int i = 0; i < 32; i += 8) {
    int n = n0 + ty + i, k = k0 + tx;
    if (n < N && k < K) dst[(size_t)n * K + k] = f2bf(t[tx][ty + i]);
  }
}

__global__ void cvt_k(const float* __restrict__ src, ushort* __restrict__ dst, int n) {
  int i = blockIdx.x * 256 + threadIdx.x;
  if (i < n) dst[i] = f2bf(src[i]);
}

// rank-1 reduction: R[v][n] = Sum_j ew[v*256+j]*W[(v*256+j)*ldw+n],
//                   C[v][n] = Sum_j eb[v*256+j]*W[...] (+ bias[v*256+n] if biasPerV)
__global__ void redw_k(const float* __restrict__ W, int ldw,
                       const float* __restrict__ ew, const float* __restrict__ eb,
                       const float* __restrict__ bias, int biasPerV,
                       float* __restrict__ R, float* __restrict__ C, int N) {
  int v = blockIdx.x;
  int n = threadIdx.x;
  if (n >= N) return;
  const float* Wb = W + (size_t)v * 256 * ldw + n;
  const float* ewv = ew + v * 256;
  const float* ebv = eb + v * 256;
  float r = 0.f, c = 0.f;
  for (int j = 0; j < 256; j++) {
    float w = Wb[(size_t)j * ldw];
    r += ewv[j] * w;
    c += ebv[j] * w;
  }
  if (biasPerV) c += bias[v * 256 + n];
  R[v * N + n] = r;
  C[v * N + n] = c;
}

// sel fc1 replacement: selH[m][n] = bf16(elu(b1[n] + Sum_v x[m,v]*R1[v,n] + C1[v,n]))
__global__ __launch_bounds__(256) void sel_h_k(const float* __restrict__ x,
                                               const float* __restrict__ R1,
                                               const float* __restrict__ C1,
                                               const float* __restrict__ b1,
                                               ushort* __restrict__ selH) {
  int m = blockIdx.x, n = threadIdx.x;
  __shared__ float xs[16];
  if (n < 16) xs[n] = x[m * 16 + n];
  __syncthreads();
  float a = b1[n];
  #pragma unroll
  for (int v = 0; v < 16; v++) a += xs[v] * R1[v * 256 + n] + C1[v * 256 + n];
  selH[(size_t)m * 256 + n] = f2bf(eluf_(a));
}

// sel skip replacement: selSkip[m][n<16] = b[n] + Sum_v x[m,v]*Rsk[v,n] + Csk[v,n]
__global__ void sel_skip_k(const float* __restrict__ x,
                           const float* __restrict__ Rsk, const float* __restrict__ Csk,
                           const float* __restrict__ b, float* __restrict__ selSkip) {
  int gid = blockIdx.x * 256 + threadIdx.x;    // BT*16
  int m = gid >> 4, n = gid & 15;
  const float* xr = x + m * 16;
  float a = b[n];
  #pragma unroll
  for (int v = 0; v < 16; v++) a += xr[v] * Rsk[v * 16 + n] + Csk[v * 16 + n];
  selSkip[gid] = a;
}

// var fc1 replacement: bufA16[z][m][n] = bf16(elu(x[m,vb+z]*R[(vb+z),n] + C[(vb+z),n]))
__global__ __launch_bounds__(256) void var_h_k(const float* __restrict__ x,
                                               const float* __restrict__ R,
                                               const float* __restrict__ C,
                                               int vbase, ushort* __restrict__ bufA16) {
  int m = blockIdx.x, n = threadIdx.x;
  const float* xr = x + m * 16 + vbase;
  #pragma unroll
  for (int z = 0; z < 4; z++) {
    int v = vbase + z;
    float a = xr[z] * R[v * 256 + n] + C[v * 256 + n];
    bufA16[((size_t)z * BT + m) * 256 + n] = f2bf(eluf_(a));
  }
}

// pack whh fp32 [2][1024][256] -> fp8 e4m3 (x64) in K=128 B-frag order.
__global__ void whh_pack8_k(const float* __restrict__ whh, unsigned char* __restrict__ dst) {
  int gid = blockIdx.x * 256 + threadIdx.x;   // 16384 total
  int layer = gid >> 13;
  int rem = gid & 8191;
  int lane = rem & 63;
  int f = (rem >> 6) & 15;
  int wave = rem >> 10;
  int kt2 = f & 1, ts = (f >> 1) & 1, g = f >> 2;
  int n = g * 256 + wave * 32 + ts * 16 + (lane & 15);
  int k0 = kt2 * 128 + (lane >> 4) * 32;
  const float* src = whh + (size_t)layer * 262144 + (size_t)n * 256 + k0;
  unsigned char* d = dst + (size_t)gid * 32;
  #pragma unroll
  for (int b = 0; b < 32; b++) {
    __hip_fp8_e4m3 q(src[b] * 64.f);
    d[b] = q.__x;
  }
}

// ---------------- bf16 MFMA GEMM ----------------
// ADT: 0 A fp32; 1 A bf16; 2 embedded-on-the-fly; 3 A = A1+A2 fp32 (A2 via embw)
template<int ADT, int ACT, int CDT>
__global__ __launch_bounds__(256) void mgemm_k(
    const void* __restrict__ Aall, int lda, long aStride,
    const ushort* __restrict__ Ball, long bStride,
    const float* __restrict__ biasAll, long biasStride,
    void* __restrict__ Call, int ldc, long cStride,
    int K, int Nvalid,
    const float* __restrict__ embw, const float* __restrict__ embb, int xbase) {
  int z = blockIdx.z;
  const ushort* B = Ball + (size_t)z * bStride;
  const float* bias = biasAll ? biasAll + (size_t)z * biasStride : nullptr;
  int m0 = blockIdx.y * 128, n0 = blockIdx.x * 128;
  __shared__ ushort As[128][40];
  __shared__ ushort Bs[128][40];
  int tid = threadIdx.x;
  int r = tid >> 1, half = tid & 1;
  int wave = tid >> 6, lane = tid & 63;
  int wm = (wave >> 1) * 64, wn = (wave & 1) * 64;
  int lm = lane & 15, lq = lane >> 4;
  floatx4 acc[4][4];
  #pragma unroll
  for (int i = 0; i < 4; i++)
    #pragma unroll
    for (int j = 0; j < 4; j++) acc[i][j] = (floatx4)0.f;

  for (int k0 = 0; k0 < K; k0 += 32) {
    int kk = k0 + half * 16;
    {
      int gm = m0 + r;
      ushort tmp[16];
      if (ADT == 0) {
        const float* Af = (const float*)Aall + (size_t)z * aStride + (size_t)gm * lda + kk;
        #pragma unroll
        for (int q = 0; q < 4; q++) {
          float4 f = ((const float4*)Af)[q];
          tmp[q * 4 + 0] = f2bf(f.x); tmp[q * 4 + 1] = f2bf(f.y);
          tmp[q * 4 + 2] = f2bf(f.z); tmp[q * 4 + 3] = f2bf(f.w);
        }
      } else if (ADT == 1) {
        const ushort* Ab = (const ushort*)Aall + (size_t)z * aStride + (size_t)gm * lda + kk;
        *(ushort8v*)&tmp[0] = *(const ushort8v*)(Ab);
        *(ushort8v*)&tmp[8] = *(const ushort8v*)(Ab + 8);
      } else if (ADT == 2) {
        const float* xp = (const float*)Aall;
        float xv = xp[(size_t)gm * lda + xbase + z + (kk >> 8)];
        const float4* ew = (const float4*)(embw + (size_t)z * 256 + kk);
        const float4* eb = (const float4*)(embb + (size_t)z * 256 + kk);
        #pragma unroll
        for (int q = 0; q < 4; q++) {
          float4 w4 = ew[q], b4 = eb[q];
          tmp[q * 4 + 0] = f2bf(xv * w4.x + b4.x); tmp[q * 4 + 1] = f2bf(xv * w4.y + b4.y);
          tmp[q * 4 + 2] = f2bf(xv * w4.z + b4.z); tmp[q * 4 + 3] = f2bf(xv * w4.w + b4.w);
        }
      } else {
        const float* A1 = (const float*)Aall + (size_t)z * aStride + (size_t)gm * lda + kk;
        const float* A2 = embw + (size_t)z * aStride + (size_t)gm * lda + kk;
        #pragma unroll
        for (int q = 0; q < 4; q++) {
          float4 f1 = ((const float4*)A1)[q];
          float4 f2 = ((const float4*)A2)[q];
          tmp[q * 4 + 0] = f2bf(f1.x + f2.x); tmp[q * 4 + 1] = f2bf(f1.y + f2.y);
          tmp[q * 4 + 2] = f2bf(f1.z + f2.z); tmp[q * 4 + 3] = f2bf(f1.w + f2.w);
        }
      }
      *(ushort8v*)&As[r][half * 16]     = *(ushort8v*)&tmp[0];
      *(ushort8v*)&As[r][half * 16 + 8] = *(ushort8v*)&tmp[8];
    }
    {
      int gn = n0 + r;
      ushort tmp[16];
      if (gn < Nvalid) {
        const ushort* Bp = B + (size_t)gn * K + kk;
        *(ushort8v*)&tmp[0] = *(const ushort8v*)(Bp);
        *(ushort8v*)&tmp[8] = *(const ushort8v*)(Bp + 8);
      } else {
        #pragma unroll
        for (int q = 0; q < 16; q++) tmp[q] = 0;
      }
      *(ushort8v*)&Bs[r][half * 16]     = *(ushort8v*)&tmp[0];
      *(ushort8v*)&Bs[r][half * 16 + 8] = *(ushort8v*)&tmp[8];
    }
    __syncthreads();
    short8 fa[4], fb[4];
    #pragma unroll
    for (int i = 0; i < 4; i++) fa[i] = *(const short8*)&As[wm + i * 16 + lm][lq * 8];
    #pragma unroll
    for (int j = 0; j < 4; j++) fb[j] = *(const short8*)&Bs[wn + j * 16 + lm][lq * 8];
    #pragma unroll
    for (int i = 0; i < 4; i++)
      #pragma unroll
      for (int j = 0; j < 4; j++)
        acc[i][j] = __builtin_amdgcn_mfma_f32_16x16x32_bf16(fa[i], fb[j], acc[i][j], 0, 0, 0);
    __syncthreads();
  }
  #pragma unroll
  for (int j = 0; j < 4; j++) {
    int gn = n0 + wn + j * 16 + lm;
    if (gn >= Nvalid) continue;
    float bv = bias ? bias[gn] : 0.f;
    #pragma unroll
    for (int i = 0; i < 4; i++) {
      #pragma unroll
      for (int rg = 0; rg < 4; rg++) {
        int gm = m0 + wm + i * 16 + lq * 4 + rg;
        float v = acc[i][j][rg] + bv;
        if (ACT == 1) v = eluf_(v);
        if (CDT == 0) ((float*)Call + (size_t)z * cStride)[(size_t)gm * ldc + gn] = v;
        else ((ushort*)Call + (size_t)z * cStride)[(size_t)gm * ldc + gn] = f2bf(v);
      }
    }
  }
}

// ---------------- selection GRN finish ----------------
__global__ void sel_finish_k(const float* __restrict__ selG, const float* __restrict__ selSkip,
                             const float* __restrict__ lng, const float* __restrict__ lnb,
                             float* __restrict__ wout, int M) {
  int m = blockIdx.x * 256 + threadIdx.x;
  if (m >= M) return;
  float s[16];
  float mean = 0.f;
  #pragma unroll
  for (int i = 0; i < 16; i++) {
    float h1 = selG[m * 32 + i], h2 = selG[m * 32 + 16 + i];
    float val = h1 * sigmoidf_(h2) + selSkip[m * 16 + i];
    s[i] = val; mean += val;
  }
  mean *= (1.f / 16.f);
  float var = 0.f;
  #pragma unroll
  for (int i = 0; i < 16; i++) { float d = s[i] - mean; var += d * d; }
  var *= (1.f / 16.f);
  float inv = rsqrtf(var + 1e-5f);
  float mx = -1e30f;
  #pragma unroll
  for (int i = 0; i < 16; i++) { s[i] = (s[i] - mean) * inv * lng[i] + lnb[i]; mx = fmaxf(mx, s[i]); }
  float sum = 0.f;
  #pragma unroll
  for (int i = 0; i < 16; i++) { s[i] = expf(s[i] - mx); sum += s[i]; }
  float isum = 1.f / sum;
  #pragma unroll
  for (int i = 0; i < 16; i++) wout[m * 16 + i] = s[i] * isum;
}

// ---------------- var-GRN epilogue, 4 variables per launch, one-pass LN ----------------
__global__ __launch_bounds__(256) void var_epi4_k(
    const ushort* __restrict__ G16,
    const float* __restrict__ x, int vbase,
    const float* __restrict__ embw, const float* __restrict__ embb,
    const float* __restrict__ lng, const float* __restrict__ lnb,
    const float* __restrict__ wts, float* __restrict__ vsn, int first) {
  int m = blockIdx.x, j = threadIdx.x;
  __shared__ float red8[8];
  float accv = 0.f;
  #pragma unroll
  for (int z = 0; z < 4; z++) {
    int v = vbase + z;
    const ushort* Gp = G16 + ((size_t)z * BT + m) * 512;
    float g1 = bf2f(Gp[j]), g2 = bf2f(Gp[256 + j]);
    float e = x[m * VV + v] * embw[z * 256 + j] + embb[z * 256 + j];
    float s = g1 * sigmoidf_(g2) + e;
    float2 r = bsum256x2(s, s * s, red8);
    float mean = r.x * (1.f / 256.f);
    float var = r.y * (1.f / 256.f) - mean * mean;
    float o = (s - mean) * rsqrtf(var + 1e-5f) * lng[z * 256 + j] + lnb[z * 256 + j];
    accv += wts[m * VV + v] * o;
  }
  size_t oi = (size_t)m * 256 + j;
  if (first) vsn[oi] = accv; else vsn[oi] += accv;
}

// ---------------- generic GRN epilogue: GLU + (skipA+skipB) + LN, one-pass ----------------
__global__ __launch_bounds__(256) void grn_epi_k(
    const ushort* __restrict__ G, const float* __restrict__ skipA,
    const float* __restrict__ skipB,
    const float* __restrict__ lng, const float* __restrict__ lnb,
    float* __restrict__ out) {
  int m = blockIdx.x, j = threadIdx.x;
  __shared__ float red8[8];
  float g1 = bf2f(G[(size_t)m * 512 + j]), g2 = bf2f(G[(size_t)m * 512 + 256 + j]);
  float sk = skipA[(size_t)m * 256 + j];
  if (skipB) sk += skipB[(size_t)m * 256 + j];
  float s = g1 * sigmoidf_(g2) + sk;
  float2 r = bsum256x2(s, s * s, red8);
  float mean = r.x * (1.f / 256.f);
  float var = r.y * (1.f / 256.f) - mean * mean;
  out[(size_t)m * 256 + j] = (s - mean) * rsqrtf(var + 1e-5f) * lng[j] + lnb[j];
}

// ---------------- elementwise ----------------
__global__ void add2_k(const float* __restrict__ a, const float* __restrict__ b,
                       float* __restrict__ c, int n) {
  int i = blockIdx.x * 256 + threadIdx.x;
  if (i < n) c[i] = a[i] + b[i];
}

// ---------------- LSTM recurrence: K=128 scaled fp8 MFMA (R8 exact core) ----------------
#define DESC (1.f / 1024.f)
#define H8S 272
__global__ __launch_bounds__(512, 2) void lstm_recur_k(
    const float* __restrict__ xi,            // [B,T,1024] = xW^T + bih + bhh
    const unsigned char* __restrict__ wpk,   // fp8 K128-frag-packed layer (262144 B)
    float* __restrict__ hout,                // [B,T,256]
    int T) {
  int bb = blockIdx.x;                        // one batch
  int tid = threadIdx.x;
  int wave = tid >> 6, lane = tid & 63;
  int lm = lane & 15, lq = lane >> 4;
  __shared__ __align__(16) unsigned char h8[2][16 * H8S];
  for (int i = tid; i < 2 * 16 * H8S / 4; i += 512) ((uint*)h8)[i] = 0;

  int8v wr[16];
  {
    const int8v* wp = (const int8v*)wpk;
    #pragma unroll
    for (int f = 0; f < 16; f++) wr[f] = wp[(wave * 16 + f) * 64 + lane];
  }
  bool act = (lq == 0);
  int jj = wave * 32 + lm;                   // ts adds +16
  const float* xg = xi + (size_t)bb * T * 1024;
  float xq[8], xn[8];
  if (act) {
    #pragma unroll
    for (int g = 0; g < 4; g++) {
      xq[2 * g]     = xg[g * 256 + jj];
      xq[2 * g + 1] = xg[g * 256 + jj + 16];
    }
  }
  float cst[2] = {0.f, 0.f};
  float hbf[2][8];
  int arow = lm * H8S + lq * 32;
  __syncthreads();

  for (int t = 0; t < T; t++) {
    int cur = t & 1, nxt = cur ^ 1;
    if (act && t + 1 < T) {
      const float* xp = xg + (size_t)(t + 1) * 1024;
      #pragma unroll
      for (int g = 0; g < 4; g++) {
        xn[2 * g]     = xp[g * 256 + jj];
        xn[2 * g + 1] = xp[g * 256 + jj + 16];
      }
    }
    int8v a[2];
    #pragma unroll
    for (int kt = 0; kt < 2; kt++)
      a[kt] = *(const int8v*)&h8[cur][arow + kt * 128];
    floatx4 acc[8];                 // f = g*2 + ts
    #pragma unroll
    for (int f = 0; f < 8; f++) acc[f] = (floatx4)0.f;
    #pragma unroll
    for (int kt = 0; kt < 2; kt++)
      #pragma unroll
      for (int f = 0; f < 8; f++)
        acc[f] = __builtin_amdgcn_mfma_scale_f32_16x16x128_f8f6f4(
            a[kt], wr[f * 2 + kt], acc[f], 0, 0, 0, 0x7f7f7f7f, 0, 0x7f7f7f7f);
    if (act) {
      int tb = t & 7;
      #pragma unroll
      for (int ts = 0; ts < 2; ts++) {
        float pi = acc[0 + ts][0] * DESC + xq[0 + ts];
        float pf = acc[2 + ts][0] * DESC + xq[2 + ts];
        float pg = acc[4 + ts][0] * DESC + xq[4 + ts];
        float po = acc[6 + ts][0] * DESC + xq[6 + ts];
        float c = fsig(pf) * cst[ts] + fsig(pi) * ftanh(pg);
        cst[ts] = c;
        hbf[ts][tb] = fsig(po) * ftanh(c);
      }
#ifdef HW_FP8_CVT
      int pk = __builtin_amdgcn_cvt_pk_fp8_f32(hbf[0][tb] * 16.f, hbf[1][tb] * 16.f, 0, false);
      h8[nxt][jj]      = (unsigned char)(pk & 0xff);
      h8[nxt][jj + 16] = (unsigned char)((pk >> 8) & 0xff);
#else
      __hip_fp8_e4m3 q0(hbf[0][tb] * 16.f), q1(hbf[1][tb] * 16.f);
      h8[nxt][jj]      = q0.__x;
      h8[nxt][jj + 16] = q1.__x;
#endif
      if (tb == 7) {
        #pragma unroll
        for (int q = 0; q < 8; q++) {
          size_t base = ((size_t)(bb * T + t - 7 + q)) * 256;
          hout[base + jj]      = hbf[0][q];
          hout[base + jj + 16] = hbf[1][q];
        }
      }
      #pragma unroll
      for (int g = 0; g < 8; g++) xq[g] = xn[g];
    }
    __syncthreads();
  }
}

// ---------------- attention, decode-style (only query t = T-1) ----------------
__global__ __launch_bounds__(256) void attn_decode_k(const float* __restrict__ qkv,
                                                     float* __restrict__ o, int T) {
  int bh = blockIdx.x; int b = bh >> 2, h = bh & 3;
  int tid = threadIdx.x;
  __shared__ float q[64];
  __shared__ float p[512];
  __shared__ float red[256];
  if (tid < 64) q[tid] = qkv[((size_t)(b * T + T - 1)) * 768 + h * 64 + tid];
  __syncthreads();
  for (int t = tid; t < 512; t += 256) {
    const float* kv = qkv + ((size_t)(b * T + t)) * 768 + 256 + h * 64;
    float s = 0.f;
    #pragma unroll 16
    for (int d = 0; d < 64; d++) s += q[d] * kv[d];
    p[t] = s * 0.125f;
  }
  __syncthreads();
  red[tid] = fmaxf(p[tid], p[tid + 256]); __syncthreads();
  for (int st = 128; st > 0; st >>= 1) { if (tid < st) red[tid] = fmaxf(red[tid], red[tid + st]); __syncthreads(); }
  float mx = red[0]; __syncthreads();
  float e0 = expf(p[tid] - mx), e1 = expf(p[tid + 256] - mx);
  red[tid] = e0 + e1; __syncthreads();
  for (int st = 128; st > 0; st >>= 1) { if (tid < st) red[tid] += red[tid + st]; __syncthreads(); }
  float inv = 1.f / red[0];
  __syncthreads();
  p[tid] = e0; p[tid + 256] = e1;
  __syncthreads();
  int d = tid & 63, grp = tid >> 6;
  float acc = 0.f;
  for (int t = grp * 128; t < grp * 128 + 128; t++)
    acc += p[t] * qkv[((size_t)(b * T + t)) * 768 + 512 + h * 64 + d];
  red[tid] = acc; __syncthreads();
  if (grp == 0)
    o[(b * 4 + h) * 64 + d] = (red[tid] + red[tid + 64] + red[tid + 128] + red[tid + 192]) * inv;
}

// ---------------- attn out-proj + residual + LN (only t=T-1) ----------------
__global__ __launch_bounds__(256) void attn_proj_ln_k(
    const float* __restrict__ attnO, const float* __restrict__ W, const float* __restrict__ bias,
    const float* __restrict__ lstmF, const float* __restrict__ lng, const float* __restrict__ lnb,
    float* __restrict__ out, int T) {
  int bb = blockIdx.x, j = threadIdx.x;
  __shared__ float a[256];
  __shared__ float red[256];
  a[j] = attnO[bb * 256 + j];
  __syncthreads();
  float acc = bias[j];
  const float* wr = W + (size_t)j * 256;
  #pragma unroll 8
  for (int k = 0; k < 256; k += 4) {
    float4 w4 = *(const float4*)(wr + k);
    acc += a[k] * w4.x + a[k + 1] * w4.y + a[k + 2] * w4.z + a[k + 3] * w4.w;
  }
  float s = acc + lstmF[((size_t)(bb * T + T - 1)) * 256 + j];
  float mean = block_sum256(s, red) * (1.f / 256.f);
  float d = s - mean;
  float var = block_sum256(d * d, red) * (1.f / 256.f);
  out[bb * 256 + j] = d * rsqrtf(var + 1e-5f) * lng[j] + lnb[j];
}

// ---------------- final two GRNs (pa then fg), only t=T-1 ----------------
__global__ __launch_bounds__(256) void final_grns_k(
    const float* __restrict__ ain,
    const float* __restrict__ paw1, const float* __restrict__ pab1,
    const float* __restrict__ paw2, const float* __restrict__ pab2,
    const float* __restrict__ palg, const float* __restrict__ palb,
    const float* __restrict__ fgw1, const float* __restrict__ fgb1,
    const float* __restrict__ fgw2, const float* __restrict__ fgb2,
    const float* __restrict__ fglg, const float* __restrict__ fglb,
    float* __restrict__ out) {
  int bb = blockIdx.x, j = threadIdx.x;
  __shared__ float a[256];
  __shared__ float hbuf[1024];
  __shared__ float red[256];
  a[j] = ain[bb * 256 + j];
  __syncthreads();
  float acc = pab1[j];
  for (int k = 0; k < 256; k++) acc += a[k] * paw1[k * 256 + j];
  hbuf[j] = eluf_(acc);
  __syncthreads();
  float g1 = pab2[j], g2 = pab2[256 + j];
  for (int k = 0; k < 256; k++) { float hv = hbuf[k]; g1 += hv * paw2[k * 512 + j]; g2 += hv * paw2[k * 512 + 256 + j]; }
  float s = g1 * sigmoidf_(g2) + a[j];
  float mean = block_sum256(s, red) * (1.f / 256.f);
  float d = s - mean;
  float var = block_sum256(d * d, red) * (1.f / 256.f);
  float af = d * rsqrtf(var + 1e-5f) * palg[j] + palb[j];
  __syncthreads();
  a[j] = af;
  __syncthreads();
  float hh[4];
  #pragma unroll
  for (int q = 0; q < 4; q++) {
    int jj = j + q * 256;
    float ac = fgb1[jj];
    for (int k = 0; k < 256; k++) ac += a[k] * fgw1[k * 1024 + jj];
    hh[q] = eluf_(ac);
  }
  __syncthreads();
  #pragma unroll
  for (int q = 0; q < 4; q++) hbuf[j + q * 256] = hh[q];
  __syncthreads();
  float G1 = fgb2[j], G2 = fgb2[256 + j];
  for (int k = 0; k < 1024; k++) { float hv = hbuf[k]; G1 += hv * fgw2[k * 512 + j]; G2 += hv * fgw2[k * 512 + 256 + j]; }
  float s2 = G1 * sigmoidf_(G2) + a[j];
  mean = block_sum256(s2, red) * (1.f / 256.f);
  d = s2 - mean;
  var = block_sum256(d * d, red) * (1.f / 256.f);
  out[bb * 256 + j] = d * rsqrtf(var + 1e-5f) * fglg[j] + fglb[j];
}

extern "C" void kernel_launch(void* const* d_in, const int* in_sizes, int n_in,
                              void* d_out, int out_size, void* d_ws, size_t ws_size,
                              hipStream_t stream) {
  const float* x          = (const float*)d_in[0];
  const float* emb_w      = (const float*)d_in[1];
  const float* emb_b      = (const float*)d_in[2];
  const float* vg_fc1_w   = (const float*)d_in[3];
  const float* vg_fc1_b   = (const float*)d_in[4];
  const float* vg_fc2_w   = (const float*)d_in[5];
  const float* vg_fc2_b   = (const float*)d_in[6];
  const float* vg_ln_g    = (const float*)d_in[7];
  const float* vg_ln_b    = (const float*)d_in[8];
  const float* sel_fc1_w  = (const float*)d_in[9];
  const float* sel_fc1_b  = (const float*)d_in[10];
  const float* sel_fc2_w  = (const float*)d_in[11];
  const float* sel_fc2_b  = (const float*)d_in[12];
  const float* sel_skip_w = (const float*)d_in[13];
  const float* sel_skip_b = (const float*)d_in[14];
  const float* sel_ln_g   = (const float*)d_in[15];
  const float* sel_ln_b   = (const float*)d_in[16];
  const float* lstm_wih   = (const float*)d_in[17];
  const float* lstm_whh   = (const float*)d_in[18];
  const float* lstm_bih   = (const float*)d_in[19];
  const float* lstm_bhh   = (const float*)d_in[20];
  const float* pl_fc1_w   = (const float*)d_in[21];
  const float* pl_fc1_b   = (const float*)d_in[22];
  const float* pl_fc2_w   = (const float*)d_in[23];
  const float* pl_fc2_b   = (const float*)d_in[24];
  const float* pl_ln_g    = (const float*)d_in[25];
  const float* pl_ln_b    = (const float*)d_in[26];
  const float* attn_in_w  = (const float*)d_in[27];
  const float* attn_in_b  = (const float*)d_in[28];
  const float* attn_out_w = (const float*)d_in[29];
  const float* attn_out_b = (const float*)d_in[30];
  const float* attn_ln_g  = (const float*)d_in[31];
  const float* attn_ln_b  = (const float*)d_in[32];
  const float* pa_fc1_w   = (const float*)d_in[33];
  const float* pa_fc1_b   = (const float*)d_in[34];
  const float* pa_fc2_w   = (const float*)d_in[35];
  const float* pa_fc2_b   = (const float*)d_in[36];
  const float* pa_ln_g    = (const float*)d_in[37];
  const float* pa_ln_b    = (const float*)d_in[38];
  const float* fg_fc1_w   = (const float*)d_in[39];
  const float* fg_fc1_b   = (const float*)d_in[40];
  const float* fg_fc2_w   = (const float*)d_in[41];
  const float* fg_fc2_b   = (const float*)d_in[42];
  const float* fg_ln_g    = (const float*)d_in[43];
  const float* fg_ln_b    = (const float*)d_in[44];
  (void)in_sizes; (void)n_in; (void)out_size; (void)ws_size;

  float* out     = (float*)d_out;
  float* out_wts = out + BB * DD;

  // ---- workspace layout ----
  char* p = (char*)d_ws;
  ushort* wt_sel_fc2  = (ushort*)p;                 p += 8192 * 2;
  ushort* wt_var_fc2  = (ushort*)p;                 p += 2097152 * 2;
  ushort* wt_wih      = (ushort*)p;                 p += 524288 * 2;
  unsigned char* wt_whh_pk8 = (unsigned char*)p;    p += 524288;
  ushort* wt_pl_fc1   = (ushort*)p;                 p += 65536 * 2;
  ushort* wt_pl_fc2   = (ushort*)p;                 p += 131072 * 2;
  ushort* wt_attn     = (ushort*)p;                 p += 196608 * 2;
  float*  selR        = (float*)p;                  p += 4096 * 4;   // [16][256]
  float*  selC        = (float*)p;                  p += 4096 * 4;
  float*  varR        = (float*)p;                  p += 4096 * 4;
  float*  varC        = (float*)p;                  p += 4096 * 4;
  float*  skR         = (float*)p;                  p += 256 * 4;    // [16][16]
  float*  skC         = (float*)p;                  p += 256 * 4;
  ushort* selH        = (ushort*)p;                 p += (size_t)BT * 256 * 2;
  float*  selSkip     = (float*)p;                  p += (size_t)BT * 16 * 4;
  float*  selG        = (float*)p;                  p += (size_t)BT * 32 * 4;
  float*  vsn         = (float*)p;                  p += (size_t)BT * 256 * 4;
  float*  hseq1       = (float*)p;                  p += (size_t)BT * 256 * 4;
  float*  hseq2       = (float*)p;                  p += (size_t)BT * 256 * 4;
  float*  cbias       = (float*)p;                  p += 4096 * 4;
  float*  attnO       = (float*)p;                  p += 8192 * 4;
  float*  attnLN      = (float*)p;                  p += 8192 * 4;
  char*   R           = p;
  ushort* bufA16 = (ushort*)R;
  ushort* bufG16 = (ushort*)(R + (((size_t)32) << 20));
  float*  xi     = (float*)R;                                // [BT,1024] fp32 = 64 MB
  ushort* plH    = (ushort*)(R + (((size_t)16) << 20));
  ushort* plG    = (ushort*)(R + (((size_t)24) << 20));
  float*  lstmF  = (float*)(R + (((size_t)48) << 20));
  float*  qkv    = (float*)R;

  dim3 blk(256);

  // ---- weight prep ----
  wtT_k<<<dim3(1, 8, 1),    blk, 0, stream>>>(sel_fc2_w,  wt_sel_fc2,  256,  32,  0, 0);
  wtT_k<<<dim3(16, 8, 16),  blk, 0, stream>>>(vg_fc2_w,   wt_var_fc2,  256,  512, 131072, 131072);
  wtT_k<<<dim3(8, 8, 1),    blk, 0, stream>>>(pl_fc1_w,   wt_pl_fc1,   256,  256, 0, 0);
  wtT_k<<<dim3(16, 8, 1),   blk, 0, stream>>>(pl_fc2_w,   wt_pl_fc2,   256,  512, 0, 0);
  cvt_k<<<2048, blk, 0, stream>>>(lstm_wih,  wt_wih, 524288);
  whh_pack8_k<<<64, blk, 0, stream>>>(lstm_whh, wt_whh_pk8);
  cvt_k<<<768,  blk, 0, stream>>>(attn_in_w, wt_attn, 196608);
  add2_k<<<8, blk, 0, stream>>>(lstm_bih, lstm_bhh, cbias, 4096);
  // rank-1 reduced weights
  redw_k<<<16, 256, 0, stream>>>(sel_fc1_w,  256, emb_w, emb_b, nullptr,   0, selR, selC, 256);
  redw_k<<<16, 256, 0, stream>>>(vg_fc1_w,   256, emb_w, emb_b, vg_fc1_b,  1, varR, varC, 256);
  redw_k<<<16, 64,  0, stream>>>(sel_skip_w, 16,  emb_w, emb_b, nullptr,   0, skR,  skC,  16);

  // ---- selection GRN -> softmax weights (fc1/skip via rank-1 collapse) ----
  sel_h_k<<<BT, blk, 0, stream>>>(x, selR, selC, sel_fc1_b, selH);
  sel_skip_k<<<1024, blk, 0, stream>>>(x, skR, skC, sel_skip_b, selSkip);
  mgemm_k<1,0,0><<<dim3(1, 128, 1), blk, 0, stream>>>(selH, 256, 0, wt_sel_fc2, 0, sel_fc2_b, 0,
      selG, 32, 0, 256, 32, nullptr, nullptr, 0);
  sel_finish_k<<<64, blk, 0, stream>>>(selG, selSkip, sel_ln_g, sel_ln_b, out_wts, BT);

  // ---- per-variable GRNs (groups of 4; fc1 via rank-1 collapse) ----
  for (int g = 0; g < 4; g++) {
    var_h_k<<<BT, blk, 0, stream>>>(x, varR, varC, g * 4, bufA16);
    mgemm_k<1,0,1><<<dim3(4, 128, 4), blk, 0, stream>>>(bufA16, 256, (long)BT * 256,
        wt_var_fc2 + (size_t)g * 4 * 131072, 131072, vg_fc2_b + g * 2048, 512,
        bufG16, 512, (long)BT * 512, 256, 512, nullptr, nullptr, 0);
    var_epi4_k<<<BT, blk, 0, stream>>>(bufG16, x, g * 4, emb_w + g * 1024, emb_b + g * 1024,
        vg_ln_g + g * 1024, vg_ln_b + g * 1024, out_wts, vsn, g == 0 ? 1 : 0);
  }

  // ---- LSTM (2 layers), fp32 xi ----
  mgemm_k<0,0,0><<<dim3(8, 128, 1), blk, 0, stream>>>(vsn, 256, 0, wt_wih, 0, cbias, 0,
      xi, 1024, 0, 256, 1024, nullptr, nullptr, 0);
  lstm_recur_k<<<32, 512, 0, stream>>>(xi, wt_whh_pk8, hseq1, TT);
  mgemm_k<0,0,0><<<dim3(8, 128, 1), blk, 0, stream>>>(hseq1, 256, 0, wt_wih + 1024 * 256, 0,
      cbias + 1024, 0, xi, 1024, 0, 256, 1024, nullptr, nullptr, 0);
  lstm_recur_k<<<32, 512, 0, stream>>>(xi, wt_whh_pk8 + 262144, hseq2, TT);

  // ---- post-LSTM gated residual (pl GRN); skip = hseq2 + vsn fused ----
  mgemm_k<3,1,1><<<dim3(2, 128, 1), blk, 0, stream>>>(hseq2, 256, 0, wt_pl_fc1, 0, pl_fc1_b, 0,
      plH, 256, 0, 256, 256, vsn, nullptr, 0);
  mgemm_k<1,0,1><<<dim3(4, 128, 1), blk, 0, stream>>>(plH, 256, 0, wt_pl_fc2, 0, pl_fc2_b, 0,
      plG, 512, 0, 256, 512, nullptr, nullptr, 0);
  grn_epi_k<<<BT, blk, 0, stream>>>(plG, hseq2, vsn, pl_ln_g, pl_ln_b, lstmF);

  // ---- attention (decode at t=T-1 only) ----
  mgemm_k<0,0,0><<<dim3(6, 128, 1), blk, 0, stream>>>(lstmF, 256, 0, wt_attn, 0, attn_in_b, 0,
      qkv, 768, 0, 256, 768, nullptr, nullptr, 0);
  attn_decode_k<<<BB * 4, blk, 0, stream>>>(qkv, attnO, TT);
  attn_proj_ln_k<<<BB, blk, 0, stream>>>(attnO, attn_out_w, attn_out_b, lstmF,
                                         attn_ln_g, attn_ln_b, attnLN, TT);

  // ---- pa GRN + fg GRN (t=T-1 only) -> first output slice ----
  final_grns_k<<<BB, blk, 0, stream>>>(attnLN,
      pa_fc1_w, pa_fc1_b, pa_fc2_w, pa_fc2_b, pa_ln_g, pa_ln_b,
      fg_fc1_w, fg_fc1_b, fg_fc2_w, fg_fc2_b, fg_ln_g, fg_ln_b,
      out);
}

// Round 12
// 2031.587 us; speedup vs baseline: 1.2510x; 1.0672x over previous
//
#include <hip/hip_runtime.h>
#include <hip/hip_bf16.h>
#include <hip/hip_fp8.h>
#include <math.h>

// TFT: B=32, T=512, V=16, D=256, H=4, L=2.  BT = 16384.
// Round 12: fully fused var-GRN stage. One kernel: A=elu(x*R+C) generated in
// staging, 64x512 bf16 MFMA vs packed W2, epilogue = bias+GLU+emb-skip+LN
// (in-register, shfl over lm-group) + weighted accumulate -> vsn. Eliminates
// bufA16/bufG16 (~700 MB round-trip) and 11 dispatches.
// Everything else = R11 (LSTM: 32 blk x 512 thr K=128 scaled fp8 MFMA, regs).

#define BT 16384
#define TT 512
#define BB 32
#define VV 16
#define DD 256

typedef unsigned short ushort;
typedef unsigned int uint;
typedef unsigned long ulong_;
typedef __attribute__((ext_vector_type(8))) short short8;
typedef __attribute__((ext_vector_type(8))) unsigned short ushort8v;
typedef __attribute__((ext_vector_type(4))) float floatx4;
typedef __attribute__((ext_vector_type(8))) int int8v;

#if __has_builtin(__builtin_amdgcn_cvt_pk_fp8_f32)
#define HW_FP8_CVT 1
#endif

__device__ __forceinline__ float sigmoidf_(float x) { return 1.f / (1.f + expf(-x)); }
__device__ __forceinline__ float eluf_(float x)     { return x > 0.f ? x : expm1f(x); }
__device__ __forceinline__ float fsig(float x) {
  return __builtin_amdgcn_rcpf(1.f + __expf(-x));
}
__device__ __forceinline__ float ftanh(float x) {
  float xc = fminf(fmaxf(x, -44.f), 44.f);
  float e = __expf(-2.f * xc);
  return (1.f - e) * __builtin_amdgcn_rcpf(1.f + e);
}
__device__ __forceinline__ ushort f2bf(float f) {
  unsigned int u = __float_as_uint(f);
  unsigned int r = u + 0x7fffu + ((u >> 16) & 1u);
  return (ushort)(r >> 16);
}
__device__ __forceinline__ float bf2f(ushort b) { return __uint_as_float(((unsigned int)b) << 16); }

// dual block-wide sum over 256 threads (one shuffle pass, one barrier pair)
__device__ __forceinline__ float2 bsum256x2(float a, float b, float* red8) {
  #pragma unroll
  for (int m = 32; m > 0; m >>= 1) { a += __shfl_xor(a, m, 64); b += __shfl_xor(b, m, 64); }
  int w = threadIdx.x >> 6;
  if ((threadIdx.x & 63) == 0) { red8[w * 2] = a; red8[w * 2 + 1] = b; }
  __syncthreads();
  float ra = red8[0] + red8[2] + red8[4] + red8[6];
  float rb = red8[1] + red8[3] + red8[5] + red8[7];
  __syncthreads();
  return make_float2(ra, rb);
}

__device__ __forceinline__ float block_sum256(float v, float* red) {
  int j = threadIdx.x;
  red[j] = v; __syncthreads();
  #pragma unroll
  for (int st = 128; st > 0; st >>= 1) {
    if (j < st) red[j] += red[j + st];
    __syncthreads();
  }
  float r = red[0];
  __syncthreads();
  return r;
}

// ---------------- weight prep ----------------
__global__ void wtT_k(const float* __restrict__ src, ushort* __restrict__ dst,
                      int K, int N, long sStride, long dStride) {
  int b = blockIdx.z;
  src += (size_t)b * sStride; dst += (size_t)b * dStride;
  __shared__ float t[32][33];
  int k0 = blockIdx.y * 32, n0 = blockIdx.x * 32;
  int tx = threadIdx.x & 31, ty = threadIdx.x >> 5;
  #pragma unroll
  for (int i = 0; i < 32; i += 8) {
    int k = k0 + ty + i, n = n0 + tx;
    t[ty + i][tx] = (k < K && n < N) ? src[(size_t)k * N + n] : 0.f;
  }
  __syncthreads();
  #pragma unroll
  for (int i = 0; i < 32; i += 8) {
    int n = n0 + ty + i, k = k0 + tx;
    if (n < N && k < K) dst[(size_t)n * K + k] = f2bf(t[tx][ty + i]);
  }
}

__global__ void cvt_k(const float* __restrict__ src, ushort* __restrict__ dst, int n) {
  int i = blockIdx.x * 256 + threadIdx.x;
  if (i < n) dst[i] = f2bf(src[i]);
}

// rank-1 reduction: R[v][n] = Sum_j ew*W, C[v][n] = Sum_j eb*W (+bias if biasPerV)
__global__ void redw_k(const float* __restrict__ W, int ldw,
                       const float* __restrict__ ew, const float* __restrict__ eb,
                       const float* __restrict__ bias, int biasPerV,
                       float* __restrict__ R, float* __restrict__ C, int N) {
  int v = blockIdx.x;
  int n = threadIdx.x;
  if (n >= N) return;
  const float* Wb = W + (size_t)v * 256 * ldw + n;
  const float* ewv = ew + v * 256;
  const float* ebv = eb + v * 256;
  float r = 0.f, c = 0.f;
  for (int j = 0; j < 256; j++) {
    float w = Wb[(size_t)j * ldw];
    r += ewv[j] * w;
    c += ebv[j] * w;
  }
  if (biasPerV) c += bias[v * 256 + n];
  R[v * N + n] = r;
  C[v * N + n] = c;
}

// sel fc1 replacement
__global__ __launch_bounds__(256) void sel_h_k(const float* __restrict__ x,
                                               const float* __restrict__ R1,
                                               const float* __restrict__ C1,
                                               const float* __restrict__ b1,
                                               ushort* __restrict__ selH) {
  int m = blockIdx.x, n = threadIdx.x;
  __shared__ float xs[16];
  if (n < 16) xs[n] = x[m * 16 + n];
  __syncthreads();
  float a = b1[n];
  #pragma unroll
  for (int v = 0; v < 16; v++) a += xs[v] * R1[v * 256 + n] + C1[v * 256 + n];
  selH[(size_t)m * 256 + n] = f2bf(eluf_(a));
}

// sel skip replacement
__global__ void sel_skip_k(const float* __restrict__ x,
                           const float* __restrict__ Rsk, const float* __restrict__ Csk,
                           const float* __restrict__ b, float* __restrict__ selSkip) {
  int gid = blockIdx.x * 256 + threadIdx.x;    // BT*16
  int m = gid >> 4, n = gid & 15;
  const float* xr = x + m * 16;
  float a = b[n];
  #pragma unroll
  for (int v = 0; v < 16; v++) a += xr[v] * Rsk[v * 16 + n] + Csk[v * 16 + n];
  selSkip[gid] = a;
}

// pack vg_fc2_w [16][256][512] fp32 -> [16][8][512][32] bf16 (per-kstep contiguous)
__global__ void w2pack_k(const float* __restrict__ src, ushort* __restrict__ dst) {
  int z = blockIdx.z, kt = blockIdx.y, n0 = blockIdx.x * 64;
  __shared__ float t[32][65];
  for (int i = threadIdx.x; i < 2048; i += 256) {
    int r = i >> 6, c = i & 63;
    t[r][c] = src[(size_t)z * 131072 + (size_t)(kt * 32 + r) * 512 + n0 + c];
  }
  __syncthreads();
  for (int i = threadIdx.x; i < 2048; i += 256) {
    int c = i >> 5, kk = i & 31;
    dst[((size_t)(z * 8 + kt) * 512 + n0 + c) * 32 + kk] = f2bf(t[kk][c]);
  }
}

// pack whh fp32 [2][1024][256] -> fp8 e4m3 (x64) in K=128 B-frag order.
__global__ void whh_pack8_k(const float* __restrict__ whh, unsigned char* __restrict__ dst) {
  int gid = blockIdx.x * 256 + threadIdx.x;   // 16384 total
  int layer = gid >> 13;
  int rem = gid & 8191;
  int lane = rem & 63;
  int f = (rem >> 6) & 15;
  int wave = rem >> 10;
  int kt2 = f & 1, ts = (f >> 1) & 1, g = f >> 2;
  int n = g * 256 + wave * 32 + ts * 16 + (lane & 15);
  int k0 = kt2 * 128 + (lane >> 4) * 32;
  const float* src = whh + (size_t)layer * 262144 + (size_t)n * 256 + k0;
  unsigned char* d = dst + (size_t)gid * 32;
  #pragma unroll
  for (int b = 0; b < 32; b++) {
    __hip_fp8_e4m3 q(src[b] * 64.f);
    d[b] = q.__x;
  }
}

// ---------------- fused var-GRN: fc1(rank-1) + fc2 MFMA + GLU + LN + weighted sum ----------------
// Grid 256 blocks (M=64 tile each) x 256 threads (4 waves; wave w owns rows
// m0+w*16..+16, all N=512 cols). Loops z=0..15; vsn tile accumulated in regs.
__global__ __launch_bounds__(256, 1) void var_fused_k(
    const float* __restrict__ x,          // [BT][16]
    const ushort* __restrict__ w2p,       // [16][8][512][32] bf16
    const float* __restrict__ fc2b,       // [16][512]
    const float* __restrict__ varR, const float* __restrict__ varC,   // [16][256]
    const float* __restrict__ embw, const float* __restrict__ embb,   // [16][256]
    const float* __restrict__ lng, const float* __restrict__ lnb,     // [16][256]
    const float* __restrict__ wts,        // [BT][16] softmax weights
    float* __restrict__ vsn) {            // [BT][256]
  int m0 = blockIdx.x * 64;
  int tid = threadIdx.x;
  int wave = tid >> 6, lane = tid & 63;
  int lm = lane & 15, lq = lane >> 4;
  __shared__ ushort As[64][40];
  __shared__ ushort Bs[512][40];
  __shared__ float xs[64][17];
  __shared__ float wss[64][17];
  for (int i = tid; i < 64 * 16; i += 256) {
    int m = i >> 4, v = i & 15;
    xs[m][v]  = x[(size_t)(m0 + m) * 16 + v];
    wss[m][v] = wts[(size_t)(m0 + m) * 16 + v];
  }
  floatx4 vac[16];
  #pragma unroll
  for (int nt = 0; nt < 16; nt++) vac[nt] = (floatx4)0.f;

  int am = tid & 63;            // A-staging row
  int ak = (tid >> 6) * 8;      // A-staging k-offset
  // prefetch z=0, kt=0
  ushort8v pf[8];
  {
    const ushort8v* s0 = (const ushort8v*)w2p + (size_t)tid * 8;
    #pragma unroll
    for (int q = 0; q < 8; q++) pf[q] = s0[q];
  }
  float4 rA0 = *(const float4*)&varR[ak];
  float4 rA1 = *(const float4*)&varR[ak + 4];
  float4 cA0 = *(const float4*)&varC[ak];
  float4 cA1 = *(const float4*)&varC[ak + 4];
  __syncthreads();

  for (int z = 0; z < 16; z++) {
    floatx4 acc[32];
    #pragma unroll
    for (int q = 0; q < 32; q++) acc[q] = (floatx4)0.f;
    float xv = xs[am][z];
    for (int kt = 0; kt < 8; kt++) {
      // stage B from prefetch regs
      int bn = tid * 2;
      *(ushort8v*)&Bs[bn][0]      = pf[0];
      *(ushort8v*)&Bs[bn][8]      = pf[1];
      *(ushort8v*)&Bs[bn][16]     = pf[2];
      *(ushort8v*)&Bs[bn][24]     = pf[3];
      *(ushort8v*)&Bs[bn + 1][0]  = pf[4];
      *(ushort8v*)&Bs[bn + 1][8]  = pf[5];
      *(ushort8v*)&Bs[bn + 1][16] = pf[6];
      *(ushort8v*)&Bs[bn + 1][24] = pf[7];
      // generate A tile
      {
        float rr[8] = {rA0.x, rA0.y, rA0.z, rA0.w, rA1.x, rA1.y, rA1.z, rA1.w};
        float cc[8] = {cA0.x, cA0.y, cA0.z, cA0.w, cA1.x, cA1.y, cA1.z, cA1.w};
        ushort tmp[8];
        #pragma unroll
        for (int q = 0; q < 8; q++) tmp[q] = f2bf(eluf_(xv * rr[q] + cc[q]));
        *(ushort8v*)&As[am][ak] = *(ushort8v*)tmp;
      }
      // prefetch next step (kt+1, or z+1 kt0)
      int nz = (kt == 7) ? z + 1 : z;
      int nk = (kt == 7) ? 0 : kt + 1;
      if (nz < 16) {
        const ushort8v* sn = (const ushort8v*)w2p + (size_t)(nz * 8 + nk) * 2048 + (size_t)tid * 8;
        #pragma unroll
        for (int q = 0; q < 8; q++) pf[q] = sn[q];
        int rb = nz * 256 + nk * 32 + ak;
        rA0 = *(const float4*)&varR[rb]; rA1 = *(const float4*)&varR[rb + 4];
        cA0 = *(const float4*)&varC[rb]; cA1 = *(const float4*)&varC[rb + 4];
      }
      __syncthreads();
      short8 fa = *(const short8*)&As[wave * 16 + lm][lq * 8];
      #pragma unroll
      for (int nt = 0; nt < 32; nt++) {
        short8 fb = *(const short8*)&Bs[nt * 16 + lm][lq * 8];
        acc[nt] = __builtin_amdgcn_mfma_f32_16x16x32_bf16(fa, fb, acc[nt], 0, 0, 0);
      }
      __syncthreads();
    }
    // ---- epilogue: bias + GLU + embedded skip + LN + weighted accumulate ----
    int strip = wave * 16;
    float xz[4], wz[4];
    #pragma unroll
    for (int rg = 0; rg < 4; rg++) {
      int r4 = strip + lq * 4 + rg;
      xz[rg] = xs[r4][z];
      wz[rg] = wss[r4][z];
    }
    float sum[4] = {0.f, 0.f, 0.f, 0.f}, sq[4] = {0.f, 0.f, 0.f, 0.f};
    #pragma unroll
    for (int nt = 0; nt < 16; nt++) {
      int col = nt * 16 + lm;
      float b1 = fc2b[z * 512 + col];
      float b2 = fc2b[z * 512 + 256 + col];
      float ew = embw[z * 256 + col];
      float eb = embb[z * 256 + col];
      #pragma unroll
      for (int rg = 0; rg < 4; rg++) {
        float h1 = acc[nt][rg] + b1;
        float h2 = acc[nt + 16][rg] + b2;
        float s = h1 * fsig(h2) + (xz[rg] * ew + eb);
        acc[nt][rg] = s;
        sum[rg] += s; sq[rg] += s * s;
      }
    }
    #pragma unroll
    for (int rg = 0; rg < 4; rg++) {
      #pragma unroll
      for (int msk = 1; msk < 16; msk <<= 1) {
        sum[rg] += __shfl_xor(sum[rg], msk, 64);
        sq[rg]  += __shfl_xor(sq[rg],  msk, 64);
      }
    }
    float mean[4], inv[4];
    #pragma unroll
    for (int rg = 0; rg < 4; rg++) {
      mean[rg] = sum[rg] * (1.f / 256.f);
      float var = sq[rg] * (1.f / 256.f) - mean[rg] * mean[rg];
      inv[rg] = rsqrtf(var + 1e-5f);
    }
    #pragma unroll
    for (int nt = 0; nt < 16; nt++) {
      int col = nt * 16 + lm;
      float g = lng[z * 256 + col];
      float b = lnb[z * 256 + col];
      #pragma unroll
      for (int rg = 0; rg < 4; rg++) {
        float o = (acc[nt][rg] - mean[rg]) * inv[rg] * g + b;
        vac[nt][rg] += wz[rg] * o;
      }
    }
  }
  // write vsn tile
  int strip = wave * 16;
  #pragma unroll
  for (int nt = 0; nt < 16; nt++) {
    #pragma unroll
    for (int rg = 0; rg < 4; rg++) {
      vsn[(size_t)(m0 + strip + lq * 4 + rg) * 256 + nt * 16 + lm] = vac[nt][rg];
    }
  }
}

// ---------------- bf16 MFMA GEMM ----------------
// ADT: 0 A fp32; 1 A bf16; 3 A = A1+A2 fp32 (A2 via embw)
template<int ADT, int ACT, int CDT>
__global__ __launch_bounds__(256) void mgemm_k(
    const void* __restrict__ Aall, int lda, long aStride,
    const ushort* __restrict__ Ball, long bStride,
    const float* __restrict__ biasAll, long biasStride,
    void* __restrict__ Call, int ldc, long cStride,
    int K, int Nvalid,
    const float* __restrict__ embw, const float* __restrict__ embb, int xbase) {
  int z = blockIdx.z;
  const ushort* B = Ball + (size_t)z * bStride;
  const float* bias = biasAll ? biasAll + (size_t)z * biasStride : nullptr;
  int m0 = blockIdx.y * 128, n0 = blockIdx.x * 128;
  __shared__ ushort As[128][40];
  __shared__ ushort Bs[128][40];
  int tid = threadIdx.x;
  int r = tid >> 1, half = tid & 1;
  int wave = tid >> 6, lane = tid & 63;
  int wm = (wave >> 1) * 64, wn = (wave & 1) * 64;
  int lm = lane & 15, lq = lane >> 4;
  floatx4 acc[4][4];
  #pragma unroll
  for (int i = 0; i < 4; i++)
    #pragma unroll
    for (int j = 0; j < 4; j++) acc[i][j] = (floatx4)0.f;

  for (int k0 = 0; k0 < K; k0 += 32) {
    int kk = k0 + half * 16;
    {
      int gm = m0 + r;
      ushort tmp[16];
      if (ADT == 0) {
        const float* Af = (const float*)Aall + (size_t)z * aStride + (size_t)gm * lda + kk;
        #pragma unroll
        for (int q = 0; q < 4; q++) {
          float4 f = ((const float4*)Af)[q];
          tmp[q * 4 + 0] = f2bf(f.x); tmp[q * 4 + 1] = f2bf(f.y);
          tmp[q * 4 + 2] = f2bf(f.z); tmp[q * 4 + 3] = f2bf(f.w);
        }
      } else if (ADT == 1) {
        const ushort* Ab = (const ushort*)Aall + (size_t)z * aStride + (size_t)gm * lda + kk;
        *(ushort8v*)&tmp[0] = *(const ushort8v*)(Ab);
        *(ushort8v*)&tmp[8] = *(const ushort8v*)(Ab + 8);
      } else {
        const float* A1 = (const float*)Aall + (size_t)z * aStride + (size_t)gm * lda + kk;
        const float* A2 = embw + (size_t)z * aStride + (size_t)gm * lda + kk;
        #pragma unroll
        for (int q = 0; q < 4; q++) {
          float4 f1 = ((const float4*)A1)[q];
          float4 f2 = ((const float4*)A2)[q];
          tmp[q * 4 + 0] = f2bf(f1.x + f2.x); tmp[q * 4 + 1] = f2bf(f1.y + f2.y);
          tmp[q * 4 + 2] = f2bf(f1.z + f2.z); tmp[q * 4 + 3] = f2bf(f1.w + f2.w);
        }
      }
      *(ushort8v*)&As[r][half * 16]     = *(ushort8v*)&tmp[0];
      *(ushort8v*)&As[r][half * 16 + 8] = *(ushort8v*)&tmp[8];
    }
    {
      int gn = n0 + r;
      ushort tmp[16];
      if (gn < Nvalid) {
        const ushort* Bp = B + (size_t)gn * K + kk;
        *(ushort8v*)&tmp[0] = *(const ushort8v*)(Bp);
        *(ushort8v*)&tmp[8] = *(const ushort8v*)(Bp + 8);
      } else {
        #pragma unroll
        for (int q = 0; q < 16; q++) tmp[q] = 0;
      }
      *(ushort8v*)&Bs[r][half * 16]     = *(ushort8v*)&tmp[0];
      *(ushort8v*)&Bs[r][half * 16 + 8] = *(ushort8v*)&tmp[8];
    }
    __syncthreads();
    short8 fa[4], fb[4];
    #pragma unroll
    for (int i = 0; i < 4; i++) fa[i] = *(const short8*)&As[wm + i * 16 + lm][lq * 8];
    #pragma unroll
    for (int j = 0; j < 4; j++) fb[j] = *(const short8*)&Bs[wn + j * 16 + lm][lq * 8];
    #pragma unroll
    for (int i = 0; i < 4; i++)
      #pragma unroll
      for (int j = 0; j < 4; j++)
        acc[i][j] = __builtin_amdgcn_mfma_f32_16x16x32_bf16(fa[i], fb[j], acc[i][j], 0, 0, 0);
    __syncthreads();
  }
  #pragma unroll
  for (int j = 0; j < 4; j++) {
    int gn = n0 + wn + j * 16 + lm;
    if (gn >= Nvalid) continue;
    float bv = bias ? bias[gn] : 0.f;
    #pragma unroll
    for (int i = 0; i < 4; i++) {
      #pragma unroll
      for (int rg = 0; rg < 4; rg++) {
        int gm = m0 + wm + i * 16 + lq * 4 + rg;
        float v = acc[i][j][rg] + bv;
        if (ACT == 1) v = eluf_(v);
        if (CDT == 0) ((float*)Call + (size_t)z * cStride)[(size_t)gm * ldc + gn] = v;
        else ((ushort*)Call + (size_t)z * cStride)[(size_t)gm * ldc + gn] = f2bf(v);
      }
    }
  }
}

// ---------------- selection GRN finish ----------------
__global__ void sel_finish_k(const float* __restrict__ selG, const float* __restrict__ selSkip,
                             const float* __restrict__ lng, const float* __restrict__ lnb,
                             float* __restrict__ wout, int M) {
  int m = blockIdx.x * 256 + threadIdx.x;
  if (m >= M) return;
  float s[16];
  float mean = 0.f;
  #pragma unroll
  for (int i = 0; i < 16; i++) {
    float h1 = selG[m * 32 + i], h2 = selG[m * 32 + 16 + i];
    float val = h1 * sigmoidf_(h2) + selSkip[m * 16 + i];
    s[i] = val; mean += val;
  }
  mean *= (1.f / 16.f);
  float var = 0.f;
  #pragma unroll
  for (int i = 0; i < 16; i++) { float d = s[i] - mean; var += d * d; }
  var *= (1.f / 16.f);
  float inv = rsqrtf(var + 1e-5f);
  float mx = -1e30f;
  #pragma unroll
  for (int i = 0; i < 16; i++) { s[i] = (s[i] - mean) * inv * lng[i] + lnb[i]; mx = fmaxf(mx, s[i]); }
  float sum = 0.f;
  #pragma unroll
  for (int i = 0; i < 16; i++) { s[i] = expf(s[i] - mx); sum += s[i]; }
  float isum = 1.f / sum;
  #pragma unroll
  for (int i = 0; i < 16; i++) wout[m * 16 + i] = s[i] * isum;
}

// ---------------- generic GRN epilogue: GLU + (skipA+skipB) + LN, one-pass ----------------
__global__ __launch_bounds__(256) void grn_epi_k(
    const ushort* __restrict__ G, const float* __restrict__ skipA,
    const float* __restrict__ skipB,
    const float* __restrict__ lng, const float* __restrict__ lnb,
    float* __restrict__ out) {
  int m = blockIdx.x, j = threadIdx.x;
  __shared__ float red8[8];
  float g1 = bf2f(G[(size_t)m * 512 + j]), g2 = bf2f(G[(size_t)m * 512 + 256 + j]);
  float sk = skipA[(size_t)m * 256 + j];
  if (skipB) sk += skipB[(size_t)m * 256 + j];
  float s = g1 * sigmoidf_(g2) + sk;
  float2 r = bsum256x2(s, s * s, red8);
  float mean = r.x * (1.f / 256.f);
  float var = r.y * (1.f / 256.f) - mean * mean;
  out[(size_t)m * 256 + j] = (s - mean) * rsqrtf(var + 1e-5f) * lng[j] + lnb[j];
}

// ---------------- elementwise ----------------
__global__ void add2_k(const float* __restrict__ a, const float* __restrict__ b,
                       float* __restrict__ c, int n) {
  int i = blockIdx.x * 256 + threadIdx.x;
  if (i < n) c[i] = a[i] + b[i];
}

// ---------------- LSTM recurrence: K=128 scaled fp8 MFMA (R8 exact core) ----------------
#define DESC (1.f / 1024.f)
#define H8S 272
__global__ __launch_bounds__(512, 2) void lstm_recur_k(
    const float* __restrict__ xi,            // [B,T,1024] = xW^T + bih + bhh
    const unsigned char* __restrict__ wpk,   // fp8 K128-frag-packed layer (262144 B)
    float* __restrict__ hout,                // [B,T,256]
    int T) {
  int bb = blockIdx.x;
  int tid = threadIdx.x;
  int wave = tid >> 6, lane = tid & 63;
  int lm = lane & 15, lq = lane >> 4;
  __shared__ __align__(16) unsigned char h8[2][16 * H8S];
  for (int i = tid; i < 2 * 16 * H8S / 4; i += 512) ((uint*)h8)[i] = 0;

  int8v wr[16];
  {
    const int8v* wp = (const int8v*)wpk;
    #pragma unroll
    for (int f = 0; f < 16; f++) wr[f] = wp[(wave * 16 + f) * 64 + lane];
  }
  bool act = (lq == 0);
  int jj = wave * 32 + lm;
  const float* xg = xi + (size_t)bb * T * 1024;
  float xq[8], xn[8];
  if (act) {
    #pragma unroll
    for (int g = 0; g < 4; g++) {
      xq[2 * g]     = xg[g * 256 + jj];
      xq[2 * g + 1] = xg[g * 256 + jj + 16];
    }
  }
  float cst[2] = {0.f, 0.f};
  float hbf[2][8];
  int arow = lm * H8S + lq * 32;
  __syncthreads();

  for (int t = 0; t < T; t++) {
    int cur = t & 1, nxt = cur ^ 1;
    if (act && t + 1 < T) {
      const float* xp = xg + (size_t)(t + 1) * 1024;
      #pragma unroll
      for (int g = 0; g < 4; g++) {
        xn[2 * g]     = xp[g * 256 + jj];
        xn[2 * g + 1] = xp[g * 256 + jj + 16];
      }
    }
    int8v a[2];
    #pragma unroll
    for (int kt = 0; kt < 2; kt++)
      a[kt] = *(const int8v*)&h8[cur][arow + kt * 128];
    floatx4 acc[8];
    #pragma unroll
    for (int f = 0; f < 8; f++) acc[f] = (floatx4)0.f;
    #pragma unroll
    for (int kt = 0; kt < 2; kt++)
      #pragma unroll
      for (int f = 0; f < 8; f++)
        acc[f] = __builtin_amdgcn_mfma_scale_f32_16x16x128_f8f6f4(
            a[kt], wr[f * 2 + kt], acc[f], 0, 0, 0, 0x7f7f7f7f, 0, 0x7f7f7f7f);
    if (act) {
      int tb = t & 7;
      #pragma unroll
      for (int ts = 0; ts < 2; ts++) {
        float pi = acc[0 + ts][0] * DESC + xq[0 + ts];
        float pf = acc[2 + ts][0] * DESC + xq[2 + ts];
        float pg = acc[4 + ts][0] * DESC + xq[4 + ts];
        float po = acc[6 + ts][0] * DESC + xq[6 + ts];
        float c = fsig(pf) * cst[ts] + fsig(pi) * ftanh(pg);
        cst[ts] = c;
        hbf[ts][tb] = fsig(po) * ftanh(c);
      }
#ifdef HW_FP8_CVT
      int pk = __builtin_amdgcn_cvt_pk_fp8_f32(hbf[0][tb] * 16.f, hbf[1][tb] * 16.f, 0, false);
      h8[nxt][jj]      = (unsigned char)(pk & 0xff);
      h8[nxt][jj + 16] = (unsigned char)((pk >> 8) & 0xff);
#else
      __hip_fp8_e4m3 q0(hbf[0][tb] * 16.f), q1(hbf[1][tb] * 16.f);
      h8[nxt][jj]      = q0.__x;
      h8[nxt][jj + 16] = q1.__x;
#endif
      if (tb == 7) {
        #pragma unroll
        for (int q = 0; q < 8; q++) {
          size_t base = ((size_t)(bb * T + t - 7 + q)) * 256;
          hout[base + jj]      = hbf[0][q];
          hout[base + jj + 16] = hbf[1][q];
        }
      }
      #pragma unroll
      for (int g = 0; g < 8; g++) xq[g] = xn[g];
    }
    __syncthreads();
  }
}

// ---------------- attention, decode-style (only query t = T-1) ----------------
__global__ __launch_bounds__(256) void attn_decode_k(const float* __restrict__ qkv,
                                                     float* __restrict__ o, int T) {
  int bh = blockIdx.x; int b = bh >> 2, h = bh & 3;
  int tid = threadIdx.x;
  __shared__ float q[64];
  __shared__ float p[512];
  __shared__ float red[256];
  if (tid < 64) q[tid] = qkv[((size_t)(b * T + T - 1)) * 768 + h * 64 + tid];
  __syncthreads();
  for (int t = tid; t < 512; t += 256) {
    const float* kv = qkv + ((size_t)(b * T + t)) * 768 + 256 + h * 64;
    float s = 0.f;
    #pragma unroll 16
    for (int d = 0; d < 64; d++) s += q[d] * kv[d];
    p[t] = s * 0.125f;
  }
  __syncthreads();
  red[tid] = fmaxf(p[tid], p[tid + 256]); __syncthreads();
  for (int st = 128; st > 0; st >>= 1) { if (tid < st) red[tid] = fmaxf(red[tid], red[tid + st]); __syncthreads(); }
  float mx = red[0]; __syncthreads();
  float e0 = expf(p[tid] - mx), e1 = expf(p[tid + 256] - mx);
  red[tid] = e0 + e1; __syncthreads();
  for (int st = 128; st > 0; st >>= 1) { if (tid < st) red[tid] += red[tid + st]; __syncthreads(); }
  float inv = 1.f / red[0];
  __syncthreads();
  p[tid] = e0; p[tid + 256] = e1;
  __syncthreads();
  int d = tid & 63, grp = tid >> 6;
  float acc = 0.f;
  for (int t = grp * 128; t < grp * 128 + 128; t++)
    acc += p[t] * qkv[((size_t)(b * T + t)) * 768 + 512 + h * 64 + d];
  red[tid] = acc; __syncthreads();
  if (grp == 0)
    o[(b * 4 + h) * 64 + d] = (red[tid] + red[tid + 64] + red[tid + 128] + red[tid + 192]) * inv;
}

// ---------------- attn out-proj + residual + LN (only t=T-1) ----------------
__global__ __launch_bounds__(256) void attn_proj_ln_k(
    const float* __restrict__ attnO, const float* __restrict__ W, const float* __restrict__ bias,
    const float* __restrict__ lstmF, const float* __restrict__ lng, const float* __restrict__ lnb,
    float* __restrict__ out, int T) {
  int bb = blockIdx.x, j = threadIdx.x;
  __shared__ float a[256];
  __shared__ float red[256];
  a[j] = attnO[bb * 256 + j];
  __syncthreads();
  float acc = bias[j];
  const float* wr = W + (size_t)j * 256;
  #pragma unroll 8
  for (int k = 0; k < 256; k += 4) {
    float4 w4 = *(const float4*)(wr + k);
    acc += a[k] * w4.x + a[k + 1] * w4.y + a[k + 2] * w4.z + a[k + 3] * w4.w;
  }
  float s = acc + lstmF[((size_t)(bb * T + T - 1)) * 256 + j];
  float mean = block_sum256(s, red) * (1.f / 256.f);
  float d = s - mean;
  float var = block_sum256(d * d, red) * (1.f / 256.f);
  out[bb * 256 + j] = d * rsqrtf(var + 1e-5f) * lng[j] + lnb[j];
}

// ---------------- final two GRNs (pa then fg), only t=T-1 ----------------
__global__ __launch_bounds__(256) void final_grns_k(
    const float* __restrict__ ain,
    const float* __restrict__ paw1, const float* __restrict__ pab1,
    const float* __restrict__ paw2, const float* __restrict__ pab2,
    const float* __restrict__ palg, const float* __restrict__ palb,
    const float* __restrict__ fgw1, const float* __restrict__ fgb1,
    const float* __restrict__ fgw2, const float* __restrict__ fgb2,
    const float* __restrict__ fglg, const float* __restrict__ fglb,
    float* __restrict__ out) {
  int bb = blockIdx.x, j = threadIdx.x;
  __shared__ float a[256];
  __shared__ float hbuf[1024];
  __shared__ float red[256];
  a[j] = ain[bb * 256 + j];
  __syncthreads();
  float acc = pab1[j];
  for (int k = 0; k < 256; k++) acc += a[k] * paw1[k * 256 + j];
  hbuf[j] = eluf_(acc);
  __syncthreads();
  float g1 = pab2[j], g2 = pab2[256 + j];
  for (int k = 0; k < 256; k++) { float hv = hbuf[k]; g1 += hv * paw2[k * 512 + j]; g2 += hv * paw2[k * 512 + 256 + j]; }
  float s = g1 * sigmoidf_(g2) + a[j];
  float mean = block_sum256(s, red) * (1.f / 256.f);
  float d = s - mean;
  float var = block_sum256(d * d, red) * (1.f / 256.f);
  float af = d * rsqrtf(var + 1e-5f) * palg[j] + palb[j];
  __syncthreads();
  a[j] = af;
  __syncthreads();
  float hh[4];
  #pragma unroll
  for (int q = 0; q < 4; q++) {
    int jj = j + q * 256;
    float ac = fgb1[jj];
    for (int k = 0; k < 256; k++) ac += a[k] * fgw1[k * 1024 + jj];
    hh[q] = eluf_(ac);
  }
  __syncthreads();
  #pragma unroll
  for (int q = 0; q < 4; q++) hbuf[j + q * 256] = hh[q];
  __syncthreads();
  float G1 = fgb2[j], G2 = fgb2[256 + j];
  for (int k = 0; k < 1024; k++) { float hv = hbuf[k]; G1 += hv * fgw2[k * 512 + j]; G2 += hv * fgw2[k * 512 + 256 + j]; }
  float s2 = G1 * sigmoidf_(G2) + a[j];
  mean = block_sum256(s2, red) * (1.f / 256.f);
  d = s2 - mean;
  var = block_sum256(d * d, red) * (1.f / 256.f);
  out[bb * 256 + j] = d * rsqrtf(var + 1e-5f) * fglg[j] + fglb[j];
}

extern "C" void kernel_launch(void* const* d_in, const int* in_sizes, int n_in,
                              void* d_out, int out_size, void* d_ws, size_t ws_size,
                              hipStream_t stream) {
  const float* x          = (const float*)d_in[0];
  const float* emb_w      = (const float*)d_in[1];
  const float* emb_b      = (const float*)d_in[2];
  const float* vg_fc1_w   = (const float*)d_in[3];
  const float* vg_fc1_b   = (const float*)d_in[4];
  const float* vg_fc2_w   = (const float*)d_in[5];
  const float* vg_fc2_b   = (const float*)d_in[6];
  const float* vg_ln_g    = (const float*)d_in[7];
  const float* vg_ln_b    = (const float*)d_in[8];
  const float* sel_fc1_w  = (const float*)d_in[9];
  const float* sel_fc1_b  = (const float*)d_in[10];
  const float* sel_fc2_w  = (const float*)d_in[11];
  const float* sel_fc2_b  = (const float*)d_in[12];
  const float* sel_skip_w = (const float*)d_in[13];
  const float* sel_skip_b = (const float*)d_in[14];
  const float* sel_ln_g   = (const float*)d_in[15];
  const float* sel_ln_b   = (const float*)d_in[16];
  const float* lstm_wih   = (const float*)d_in[17];
  const float* lstm_whh   = (const float*)d_in[18];
  const float* lstm_bih   = (const float*)d_in[19];
  const float* lstm_bhh   = (const float*)d_in[20];
  const float* pl_fc1_w   = (const float*)d_in[21];
  const float* pl_fc1_b   = (const float*)d_in[22];
  const float* pl_fc2_w   = (const float*)d_in[23];
  const float* pl_fc2_b   = (const float*)d_in[24];
  const float* pl_ln_g    = (const float*)d_in[25];
  const float* pl_ln_b    = (const float*)d_in[26];
  const float* attn_in_w  = (const float*)d_in[27];
  const float* attn_in_b  = (const float*)d_in[28];
  const float* attn_out_w = (const float*)d_in[29];
  const float* attn_out_b = (const float*)d_in[30];
  const float* attn_ln_g  = (const float*)d_in[31];
  const float* attn_ln_b  = (const float*)d_in[32];
  const float* pa_fc1_w   = (const float*)d_in[33];
  const float* pa_fc1_b   = (const float*)d_in[34];
  const float* pa_fc2_w   = (const float*)d_in[35];
  const float* pa_fc2_b   = (const float*)d_in[36];
  const float* pa_ln_g    = (const float*)d_in[37];
  const float* pa_ln_b    = (const float*)d_in[38];
  const float* fg_fc1_w   = (const float*)d_in[39];
  const float* fg_fc1_b   = (const float*)d_in[40];
  const float* fg_fc2_w   = (const float*)d_in[41];
  const float* fg_fc2_b   = (const float*)d_in[42];
  const float* fg_ln_g    = (const float*)d_in[43];
  const float* fg_ln_b    = (const float*)d_in[44];
  (void)in_sizes; (void)n_in; (void)out_size; (void)ws_size;

  float* out     = (float*)d_out;
  float* out_wts = out + BB * DD;

  // ---- workspace layout ----
  char* p = (char*)d_ws;
  ushort* wt_sel_fc2  = (ushort*)p;                 p += 8192 * 2;
  ushort* wt_var_fc2p = (ushort*)p;                 p += 2097152 * 2;   // packed [16][8][512][32]
  ushort* wt_wih      = (ushort*)p;                 p += 524288 * 2;
  unsigned char* wt_whh_pk8 = (unsigned char*)p;    p += 524288;
  ushort* wt_pl_fc1   = (ushort*)p;                 p += 65536 * 2;
  ushort* wt_pl_fc2   = (ushort*)p;                 p += 131072 * 2;
  ushort* wt_attn     = (ushort*)p;                 p += 196608 * 2;
  float*  selR        = (float*)p;                  p += 4096 * 4;
  float*  selC        = (float*)p;                  p += 4096 * 4;
  float*  varR        = (float*)p;                  p += 4096 * 4;
  float*  varC        = (float*)p;                  p += 4096 * 4;
  float*  skR         = (float*)p;                  p += 256 * 4;
  float*  skC         = (float*)p;                  p += 256 * 4;
  ushort* selH        = (ushort*)p;                 p += (size_t)BT * 256 * 2;
  float*  selSkip     = (float*)p;                  p += (size_t)BT * 16 * 4;
  float*  selG        = (float*)p;                  p += (size_t)BT * 32 * 4;
  float*  vsn         = (float*)p;                  p += (size_t)BT * 256 * 4;
  float*  hseq1       = (float*)p;                  p += (size_t)BT * 256 * 4;
  float*  hseq2       = (float*)p;                  p += (size_t)BT * 256 * 4;
  float*  cbias       = (float*)p;                  p += 4096 * 4;
  float*  attnO       = (float*)p;                  p += 8192 * 4;
  float*  attnLN      = (float*)p;                  p += 8192 * 4;
  char*   R           = p;
  float*  xi     = (float*)R;                                // [BT,1024] fp32 = 64 MB
  ushort* plH    = (ushort*)(R + (((size_t)16) << 20));
  ushort* plG    = (ushort*)(R + (((size_t)24) << 20));
  float*  lstmF  = (float*)(R + (((size_t)48) << 20));
  float*  qkv    = (float*)R;

  dim3 blk(256);

  // ---- weight prep ----
  wtT_k<<<dim3(1, 8, 1),    blk, 0, stream>>>(sel_fc2_w,  wt_sel_fc2,  256,  32,  0, 0);
  w2pack_k<<<dim3(8, 8, 16), blk, 0, stream>>>(vg_fc2_w, wt_var_fc2p);
  wtT_k<<<dim3(8, 8, 1),    blk, 0, stream>>>(pl_fc1_w,   wt_pl_fc1,   256,  256, 0, 0);
  wtT_k<<<dim3(16, 8, 1),   blk, 0, stream>>>(pl_fc2_w,   wt_pl_fc2,   256,  512, 0, 0);
  cvt_k<<<2048, blk, 0, stream>>>(lstm_wih,  wt_wih, 524288);
  whh_pack8_k<<<64, blk, 0, stream>>>(lstm_whh, wt_whh_pk8);
  cvt_k<<<768,  blk, 0, stream>>>(attn_in_w, wt_attn, 196608);
  add2_k<<<8, blk, 0, stream>>>(lstm_bih, lstm_bhh, cbias, 4096);
  // rank-1 reduced weights
  redw_k<<<16, 256, 0, stream>>>(sel_fc1_w,  256, emb_w, emb_b, nullptr,   0, selR, selC, 256);
  redw_k<<<16, 256, 0, stream>>>(vg_fc1_w,   256, emb_w, emb_b, vg_fc1_b,  1, varR, varC, 256);
  redw_k<<<16, 64,  0, stream>>>(sel_skip_w, 16,  emb_w, emb_b, nullptr,   0, skR,  skC,  16);

  // ---- selection GRN -> softmax weights ----
  sel_h_k<<<BT, blk, 0, stream>>>(x, selR, selC, sel_fc1_b, selH);
  sel_skip_k<<<1024, blk, 0, stream>>>(x, skR, skC, sel_skip_b, selSkip);
  mgemm_k<1,0,0><<<dim3(1, 128, 1), blk, 0, stream>>>(selH, 256, 0, wt_sel_fc2, 0, sel_fc2_b, 0,
      selG, 32, 0, 256, 32, nullptr, nullptr, 0);
  sel_finish_k<<<64, blk, 0, stream>>>(selG, selSkip, sel_ln_g, sel_ln_b, out_wts, BT);

  // ---- fused var-GRN stage (all 16 variables, one kernel) ----
  var_fused_k<<<BT / 64, blk, 0, stream>>>(x, wt_var_fc2p, vg_fc2_b, varR, varC,
      emb_w, emb_b, vg_ln_g, vg_ln_b, out_wts, vsn);

  // ---- LSTM (2 layers), fp32 xi ----
  mgemm_k<0,0,0><<<dim3(8, 128, 1), blk, 0, stream>>>(vsn, 256, 0, wt_wih, 0, cbias, 0,
      xi, 1024, 0, 256, 1024, nullptr, nullptr, 0);
  lstm_recur_k<<<32, 512, 0, stream>>>(xi, wt_whh_pk8, hseq1, TT);
  mgemm_k<0,0,0><<<dim3(8, 128, 1), blk, 0, stream>>>(hseq1, 256, 0, wt_wih + 1024 * 256, 0,
      cbias + 1024, 0, xi, 1024, 0, 256, 1024, nullptr, nullptr, 0);
  lstm_recur_k<<<32, 512, 0, stream>>>(xi, wt_whh_pk8 + 262144, hseq2, TT);

  // ---- post-LSTM gated residual (pl GRN); skip = hseq2 + vsn fused ----
  mgemm_k<3,1,1><<<dim3(2, 128, 1), blk, 0, stream>>>(hseq2, 256, 0, wt_pl_fc1, 0, pl_fc1_b, 0,
      plH, 256, 0, 256, 256, vsn, nullptr, 0);
  mgemm_k<1,0,1><<<dim3(4, 128, 1), blk, 0, stream>>>(plH, 256, 0, wt_pl_fc2, 0, pl_fc2_b, 0,
      plG, 512, 0, 256, 512, nullptr, nullptr, 0);
  grn_epi_k<<<BT, blk, 0, stream>>>(plG, hseq2, vsn, pl_ln_g, pl_ln_b, lstmF);

  // ---- attention (decode at t=T-1 only) ----
  mgemm_k<0,0,0><<<dim3(6, 128, 1), blk, 0, stream>>>(lstmF, 256, 0, wt_attn, 0, attn_in_b, 0,
      qkv, 768, 0, 256, 768, nullptr, nullptr, 0);
  attn_decode_k<<<BB * 4, blk, 0, stream>>>(qkv, attnO, TT);
  attn_proj_ln_k<<<BB, blk, 0, stream>>>(attnO, attn_out_w, attn_out_b, lstmF,
                                         attn_ln_g, attn_ln_b, attnLN, TT);

  // ---- pa GRN + fg GRN (t=T-1 only) -> first output slice ----
  final_grns_k<<<BB, blk, 0, stream>>>(attnLN,
      pa_fc1_w, pa_fc1_b, pa_fc2_w, pa_fc2_b, pa_ln_g, pa_ln_b,
      fg_fc1_w, fg_fc1_b, fg_fc2_w, fg_fc2_b, fg_ln_g, fg_ln_b,
      out);
}